// Round 7
// baseline (735.969 us; speedup 1.0000x reference)
//
#include <hip/hip_runtime.h>
#include <math.h>

// GAT (2 layers) on MI355X — CSR + degree-bucketed aggregation.
// small (deg<=16): one node per 16-lane group, 4 nodes/wave, LDS alpha/src,
//                  gather unroll 4 (16 streams/wave).
// big (deg>16):    one node per wave; deg<=64 lane-per-edge softmax + LDS
//                  alpha/src, gather 16 edges in flight; deg>64 strided fallback.
// All shfls run at full segment occupancy; LDS staging avoids shfl exec-mask
// hazards entirely in gather loops.

#define NEG_SLOPE 0.2f

__device__ __forceinline__ float leaky(float v) { return v > 0.f ? v : NEG_SLOPE * v; }

// ---------------- CSR build ----------------
__global__ __launch_bounds__(256) void hist_k(const int* __restrict__ ei, int E, int ET,
                                              int* __restrict__ cnt) {
  int e = blockIdx.x * 256 + threadIdx.x;
  if (e >= ET) return;
  int d = (e < E) ? ei[E + e] : (e - E);
  atomicAdd(&cnt[d], 1);
}

__global__ __launch_bounds__(256) void scan1_k(const int* __restrict__ cnt,
                                               int* __restrict__ rowtmp,
                                               int* __restrict__ bsum, int N) {
  int i = blockIdx.x * 256 + threadIdx.x;
  int v = (i < N) ? cnt[i] : 0;
  __shared__ int sm[256];
  sm[threadIdx.x] = v;
  __syncthreads();
  #pragma unroll
  for (int off = 1; off < 256; off <<= 1) {
    int t = (threadIdx.x >= off) ? sm[threadIdx.x - off] : 0;
    __syncthreads();
    sm[threadIdx.x] += t;
    __syncthreads();
  }
  if (i < N) rowtmp[i] = sm[threadIdx.x] - v;
  if (threadIdx.x == 255) bsum[blockIdx.x] = sm[255];
}

__global__ __launch_bounds__(256) void scan2_k(int* __restrict__ bsum, int nb) {
  __shared__ int sm[256];
  int v = (threadIdx.x < nb) ? bsum[threadIdx.x] : 0;
  sm[threadIdx.x] = v;
  __syncthreads();
  #pragma unroll
  for (int off = 1; off < 256; off <<= 1) {
    int t = (threadIdx.x >= off) ? sm[threadIdx.x - off] : 0;
    __syncthreads();
    sm[threadIdx.x] += t;
    __syncthreads();
  }
  if (threadIdx.x < nb) bsum[threadIdx.x] = sm[threadIdx.x] - v;
}

// pass 3: rowptr/cursor + degree buckets
__global__ __launch_bounds__(256) void scan3_k(const int* __restrict__ rowtmp,
                                               const int* __restrict__ bsum,
                                               const int* __restrict__ cnt,
                                               int* __restrict__ rowptr,
                                               int* __restrict__ cursor,
                                               int* __restrict__ small_list,
                                               int* __restrict__ big_list,
                                               int* __restrict__ lcnt,
                                               int N, int ET) {
  int i = blockIdx.x * 256 + threadIdx.x;
  if (i < N) {
    int v = rowtmp[i] + bsum[blockIdx.x];
    rowptr[i] = v;
    cursor[i] = v;
    int deg = cnt[i];
    if (deg <= 16) { int p = atomicAdd(&lcnt[0], 1); small_list[p] = i; }
    else           { int p = atomicAdd(&lcnt[1], 1); big_list[p]   = i; }
  }
  if (i == 0) rowptr[N] = ET;
}

__global__ __launch_bounds__(256) void scatter_k(const int* __restrict__ ei, int E, int ET,
                                                 int* __restrict__ cursor,
                                                 int* __restrict__ srcs) {
  int e = blockIdx.x * 256 + threadIdx.x;
  if (e >= ET) return;
  int s, d;
  if (e < E) { s = ei[e]; d = ei[E + e]; } else { s = d = e - E; }
  int pos = atomicAdd(&cursor[d], 1);
  srcs[pos] = s;
}

// ---------------- GEMM1 + alpha1 ----------------
__global__ __launch_bounds__(256) void gemm1_k(const float* __restrict__ X,
                                               const float* __restrict__ W,
                                               const float* __restrict__ aw_s,
                                               const float* __restrict__ aw_d,
                                               float* __restrict__ Hout,
                                               float* __restrict__ as,
                                               float* __restrict__ ad, int N) {
  __shared__ float wl[32 * 128];
  __shared__ float xt[32][72];
  int cl = threadIdx.x & 31, rg = threadIdx.x >> 5;
  int c4 = cl * 4;
  int n0 = blockIdx.x * 64;
  float acc[8][4] = {};
  const float4* X4 = (const float4*)X;
  const float4* W4 = (const float4*)W;
  for (int k0 = 0; k0 < 128; k0 += 32) {
    __syncthreads();
    for (int i = threadIdx.x; i < 1024; i += 256)
      ((float4*)wl)[i] = W4[k0 * 32 + i];
    for (int i = threadIdx.x; i < 512; i += 256) {
      int r = i >> 3, kk4 = (i & 7) * 4;
      int n = n0 + r;
      float4 xv = (n < N) ? X4[(size_t)n * 32 + (k0 >> 2) + (i & 7)]
                          : make_float4(0.f, 0.f, 0.f, 0.f);
      xt[kk4 + 0][r] = xv.x; xt[kk4 + 1][r] = xv.y;
      xt[kk4 + 2][r] = xv.z; xt[kk4 + 3][r] = xv.w;
    }
    __syncthreads();
    #pragma unroll 8
    for (int kk = 0; kk < 32; ++kk) {
      float4 w4 = *(const float4*)&wl[kk * 128 + c4];
      float4 xa = *(const float4*)&xt[kk][rg * 8];
      float4 xb = *(const float4*)&xt[kk][rg * 8 + 4];
      float xr[8] = {xa.x, xa.y, xa.z, xa.w, xb.x, xb.y, xb.z, xb.w};
      #pragma unroll
      for (int j = 0; j < 8; ++j) {
        acc[j][0] += xr[j] * w4.x; acc[j][1] += xr[j] * w4.y;
        acc[j][2] += xr[j] * w4.z; acc[j][3] += xr[j] * w4.w;
      }
    }
  }
  float4 aws = *(const float4*)&aw_s[c4];
  float4 awd = *(const float4*)&aw_d[c4];
  #pragma unroll
  for (int j = 0; j < 8; ++j) {
    int n = n0 + rg * 8 + j;
    float ps = acc[j][0] * aws.x + acc[j][1] * aws.y + acc[j][2] * aws.z + acc[j][3] * aws.w;
    float pd = acc[j][0] * awd.x + acc[j][1] * awd.y + acc[j][2] * awd.z + acc[j][3] * awd.w;
    ps += __shfl_xor(ps, 1); ps += __shfl_xor(ps, 2); ps += __shfl_xor(ps, 4);
    pd += __shfl_xor(pd, 1); pd += __shfl_xor(pd, 2); pd += __shfl_xor(pd, 4);
    if (n < N) {
      *(float4*)&Hout[(size_t)n * 128 + c4] =
          make_float4(acc[j][0], acc[j][1], acc[j][2], acc[j][3]);
      if ((cl & 7) == 0) {
        as[n * 4 + (cl >> 3)] = ps;
        ad[n * 4 + (cl >> 3)] = pd;
      }
    }
  }
}

// ---------------- GEMM2 + alpha2 ----------------
__global__ __launch_bounds__(256) void gemm2_k(const float* __restrict__ X,
                                               const float* __restrict__ W,
                                               const float* __restrict__ aw_s,
                                               const float* __restrict__ aw_d,
                                               float* __restrict__ Hout,
                                               float* __restrict__ as,
                                               float* __restrict__ ad, int N) {
  __shared__ float wl[32 * 64];
  __shared__ float xt[32][72];
  int cl = threadIdx.x & 15, rg = threadIdx.x >> 4;
  int c4 = cl * 4;
  int n0 = blockIdx.x * 64;
  float acc[4][4] = {};
  const float4* X4 = (const float4*)X;
  const float4* W4 = (const float4*)W;
  for (int k0 = 0; k0 < 128; k0 += 32) {
    __syncthreads();
    for (int i = threadIdx.x; i < 512; i += 256)
      ((float4*)wl)[i] = W4[k0 * 16 + i];
    for (int i = threadIdx.x; i < 512; i += 256) {
      int r = i >> 3, kk4 = (i & 7) * 4;
      int n = n0 + r;
      float4 xv = (n < N) ? X4[(size_t)n * 32 + (k0 >> 2) + (i & 7)]
                          : make_float4(0.f, 0.f, 0.f, 0.f);
      xt[kk4 + 0][r] = xv.x; xt[kk4 + 1][r] = xv.y;
      xt[kk4 + 2][r] = xv.z; xt[kk4 + 3][r] = xv.w;
    }
    __syncthreads();
    #pragma unroll 8
    for (int kk = 0; kk < 32; ++kk) {
      float4 w4 = *(const float4*)&wl[kk * 64 + c4];
      float4 xa = *(const float4*)&xt[kk][rg * 4];
      float xr[4] = {xa.x, xa.y, xa.z, xa.w};
      #pragma unroll
      for (int j = 0; j < 4; ++j) {
        acc[j][0] += xr[j] * w4.x; acc[j][1] += xr[j] * w4.y;
        acc[j][2] += xr[j] * w4.z; acc[j][3] += xr[j] * w4.w;
      }
    }
  }
  float4 aws = *(const float4*)&aw_s[c4];
  float4 awd = *(const float4*)&aw_d[c4];
  #pragma unroll
  for (int j = 0; j < 4; ++j) {
    int n = n0 + rg * 4 + j;
    float ps = acc[j][0] * aws.x + acc[j][1] * aws.y + acc[j][2] * aws.z + acc[j][3] * aws.w;
    float pd = acc[j][0] * awd.x + acc[j][1] * awd.y + acc[j][2] * awd.z + acc[j][3] * awd.w;
    ps += __shfl_xor(ps, 1); ps += __shfl_xor(ps, 2);
    ps += __shfl_xor(ps, 4); ps += __shfl_xor(ps, 8);
    pd += __shfl_xor(pd, 1); pd += __shfl_xor(pd, 2);
    pd += __shfl_xor(pd, 4); pd += __shfl_xor(pd, 8);
    if (n < N) {
      *(float4*)&Hout[(size_t)n * 64 + c4] =
          make_float4(acc[j][0], acc[j][1], acc[j][2], acc[j][3]);
      if (cl == 0) { as[n] = ps; ad[n] = pd; }
    }
  }
}

// ---------------- layer-1 small aggregation: node per 16-lane group ----------------
__global__ __launch_bounds__(256) void agg1_small_k(const int* __restrict__ rowptr,
                                                    const int* __restrict__ srcs,
                                                    const float* __restrict__ as,
                                                    const float* __restrict__ ad,
                                                    const float* __restrict__ Hm,
                                                    const float* __restrict__ bias,
                                                    float* __restrict__ out,
                                                    const int* __restrict__ small_list,
                                                    const int* __restrict__ lcnt) {
  __shared__ float al_sm[16][17][4];   // stride 68 words spreads group banks
  __shared__ int   sr_sm[16][16];
  int g  = threadIdx.x >> 4;
  int gl = threadIdx.x & 15;
  int gidx = blockIdx.x * 16 + g;
  if (gidx >= lcnt[0]) return;
  int n = small_list[gidx];
  int r0 = rowptr[n];
  int deg = rowptr[n + 1] - r0;        // 1..16
  float4 adn = *(const float4*)&ad[n * 4];

  float e0 = -INFINITY, e1 = -INFINITY, e2 = -INFINITY, e3 = -INFINITY;
  int s = 0;
  if (gl < deg) {
    s = srcs[r0 + gl];
    float4 av = *(const float4*)&as[s * 4];
    e0 = leaky(av.x + adn.x); e1 = leaky(av.y + adn.y);
    e2 = leaky(av.z + adn.z); e3 = leaky(av.w + adn.w);
  }
  sr_sm[g][gl] = s;
  float m0 = e0, m1 = e1, m2 = e2, m3 = e3;
  #pragma unroll
  for (int off = 8; off > 0; off >>= 1) {
    m0 = fmaxf(m0, __shfl_xor(m0, off, 16)); m1 = fmaxf(m1, __shfl_xor(m1, off, 16));
    m2 = fmaxf(m2, __shfl_xor(m2, off, 16)); m3 = fmaxf(m3, __shfl_xor(m3, off, 16));
  }
  float sc0 = (gl < deg) ? __expf(e0 - m0) : 0.f;
  float sc1 = (gl < deg) ? __expf(e1 - m1) : 0.f;
  float sc2 = (gl < deg) ? __expf(e2 - m2) : 0.f;
  float sc3 = (gl < deg) ? __expf(e3 - m3) : 0.f;
  float s0 = sc0, s1 = sc1, s2 = sc2, s3 = sc3;
  #pragma unroll
  for (int off = 8; off > 0; off >>= 1) {
    s0 += __shfl_xor(s0, off, 16); s1 += __shfl_xor(s1, off, 16);
    s2 += __shfl_xor(s2, off, 16); s3 += __shfl_xor(s3, off, 16);
  }
  *(float4*)&al_sm[g][gl][0] =
      make_float4(sc0 / s0, sc1 / s1, sc2 / s2, sc3 / s3);

  int h = gl >> 2;
  int cbase = gl * 8;
  float a0 = 0.f, a1 = 0.f, a2 = 0.f, a3 = 0.f,
        a4 = 0.f, a5 = 0.f, a6 = 0.f, a7 = 0.f;
  for (int j = 0; j < deg; j += 4) {
    #pragma unroll
    for (int u = 0; u < 4; ++u) {
      int idx = j + u;
      bool vU = idx < deg;
      int jj = vU ? idx : 0;
      int   sU  = sr_sm[g][jj];
      float alU = vU ? al_sm[g][jj][h] : 0.f;
      const float* row = &Hm[(size_t)sU * 128 + cbase];
      float4 h0 = *(const float4*)row;
      float4 h1 = *(const float4*)(row + 4);
      a0 += h0.x * alU; a1 += h0.y * alU; a2 += h0.z * alU; a3 += h0.w * alU;
      a4 += h1.x * alU; a5 += h1.y * alU; a6 += h1.z * alU; a7 += h1.w * alU;
    }
  }
  float4 b0 = *(const float4*)&bias[cbase];
  float4 b1 = *(const float4*)&bias[cbase + 4];
  float4 o0, o1;
  o0.x = fmaxf(a0 + b0.x, 0.f); o0.y = fmaxf(a1 + b0.y, 0.f);
  o0.z = fmaxf(a2 + b0.z, 0.f); o0.w = fmaxf(a3 + b0.w, 0.f);
  o1.x = fmaxf(a4 + b1.x, 0.f); o1.y = fmaxf(a5 + b1.y, 0.f);
  o1.z = fmaxf(a6 + b1.z, 0.f); o1.w = fmaxf(a7 + b1.w, 0.f);
  *(float4*)&out[(size_t)n * 128 + cbase] = o0;
  *(float4*)&out[(size_t)n * 128 + cbase + 4] = o1;
}

// ---------------- layer-1 big aggregation: node per wave ----------------
__global__ __launch_bounds__(256) void agg1_big_k(const int* __restrict__ rowptr,
                                                  const int* __restrict__ srcs,
                                                  const float* __restrict__ as,
                                                  const float* __restrict__ ad,
                                                  const float* __restrict__ Hm,
                                                  const float* __restrict__ bias,
                                                  float* __restrict__ out,
                                                  const int* __restrict__ big_list,
                                                  const int* __restrict__ lcnt) {
  __shared__ float al_sm[4][64][4];
  __shared__ int   sr_sm[4][64];
  int wv = threadIdx.x >> 6, lane = threadIdx.x & 63;
  int widx = blockIdx.x * 4 + wv;
  if (widx >= lcnt[1]) return;
  int n = big_list[widx];
  int r0 = rowptr[n], r1 = rowptr[n + 1];
  int deg = r1 - r0;
  int grp = lane >> 4, gl = lane & 15, h = gl >> 2;
  int cbase = gl * 8;
  float4 adn = *(const float4*)&ad[n * 4];

  float a0 = 0.f, a1 = 0.f, a2 = 0.f, a3 = 0.f,
        a4 = 0.f, a5 = 0.f, a6 = 0.f, a7 = 0.f;

  if (deg <= 64) {
    float e0 = -INFINITY, e1 = -INFINITY, e2 = -INFINITY, e3 = -INFINITY;
    int s = 0;
    if (lane < deg) {
      s = srcs[r0 + lane];
      float4 av = *(const float4*)&as[s * 4];
      e0 = leaky(av.x + adn.x); e1 = leaky(av.y + adn.y);
      e2 = leaky(av.z + adn.z); e3 = leaky(av.w + adn.w);
    }
    sr_sm[wv][lane] = s;
    float m0 = e0, m1 = e1, m2 = e2, m3 = e3;
    #pragma unroll
    for (int off = 32; off > 0; off >>= 1) {
      m0 = fmaxf(m0, __shfl_xor(m0, off)); m1 = fmaxf(m1, __shfl_xor(m1, off));
      m2 = fmaxf(m2, __shfl_xor(m2, off)); m3 = fmaxf(m3, __shfl_xor(m3, off));
    }
    float sc0 = (lane < deg) ? __expf(e0 - m0) : 0.f;
    float sc1 = (lane < deg) ? __expf(e1 - m1) : 0.f;
    float sc2 = (lane < deg) ? __expf(e2 - m2) : 0.f;
    float sc3 = (lane < deg) ? __expf(e3 - m3) : 0.f;
    float s0 = sc0, s1 = sc1, s2 = sc2, s3 = sc3;
    #pragma unroll
    for (int off = 32; off > 0; off >>= 1) {
      s0 += __shfl_xor(s0, off); s1 += __shfl_xor(s1, off);
      s2 += __shfl_xor(s2, off); s3 += __shfl_xor(s3, off);
    }
    *(float4*)&al_sm[wv][lane][0] =
        make_float4(sc0 / s0, sc1 / s1, sc2 / s2, sc3 / s3);

    for (int base = 0; base < deg; base += 16) {
      #pragma unroll
      for (int u = 0; u < 4; ++u) {
        int idx = base + grp * 4 + u;
        bool vU = idx < deg;
        int jj = vU ? idx : 0;
        int   sU  = sr_sm[wv][jj];
        float alU = vU ? al_sm[wv][jj][h] : 0.f;
        const float* row = &Hm[(size_t)sU * 128 + cbase];
        float4 h0 = *(const float4*)row;
        float4 h1 = *(const float4*)(row + 4);
        a0 += h0.x * alU; a1 += h0.y * alU; a2 += h0.z * alU; a3 += h0.w * alU;
        a4 += h1.x * alU; a5 += h1.y * alU; a6 += h1.z * alU; a7 += h1.w * alU;
      }
    }
  } else {
    float m0 = -INFINITY, m1 = -INFINITY, m2 = -INFINITY, m3 = -INFINITY;
    for (int r = r0 + lane; r < r1; r += 64) {
      int s = srcs[r];
      float4 av = *(const float4*)&as[s * 4];
      m0 = fmaxf(m0, leaky(av.x + adn.x)); m1 = fmaxf(m1, leaky(av.y + adn.y));
      m2 = fmaxf(m2, leaky(av.z + adn.z)); m3 = fmaxf(m3, leaky(av.w + adn.w));
    }
    #pragma unroll
    for (int off = 32; off > 0; off >>= 1) {
      m0 = fmaxf(m0, __shfl_xor(m0, off)); m1 = fmaxf(m1, __shfl_xor(m1, off));
      m2 = fmaxf(m2, __shfl_xor(m2, off)); m3 = fmaxf(m3, __shfl_xor(m3, off));
    }
    float s0 = 0.f, s1 = 0.f, s2 = 0.f, s3 = 0.f;
    for (int r = r0 + lane; r < r1; r += 64) {
      int s = srcs[r];
      float4 av = *(const float4*)&as[s * 4];
      s0 += __expf(leaky(av.x + adn.x) - m0); s1 += __expf(leaky(av.y + adn.y) - m1);
      s2 += __expf(leaky(av.z + adn.z) - m2); s3 += __expf(leaky(av.w + adn.w) - m3);
    }
    #pragma unroll
    for (int off = 32; off > 0; off >>= 1) {
      s0 += __shfl_xor(s0, off); s1 += __shfl_xor(s1, off);
      s2 += __shfl_xor(s2, off); s3 += __shfl_xor(s3, off);
    }
    float mhh = (h == 0) ? m0 : (h == 1) ? m1 : (h == 2) ? m2 : m3;
    float inv = 1.f / ((h == 0) ? s0 : (h == 1) ? s1 : (h == 2) ? s2 : s3);
    float adh = (h == 0) ? adn.x : (h == 1) ? adn.y : (h == 2) ? adn.z : adn.w;
    for (int r = r0; r < r1; r += 8) {
      int rA = r + grp, rB = rA + 4;
      bool vA = rA < r1, vB = rB < r1;
      int sA = srcs[vA ? rA : r0];
      int sB = srcs[vB ? rB : r0];
      float avA = as[sA * 4 + h], avB = as[sB * 4 + h];
      float alA = vA ? (__expf(leaky(avA + adh) - mhh) * inv) : 0.f;
      float alB = vB ? (__expf(leaky(avB + adh) - mhh) * inv) : 0.f;
      const float* rowA = &Hm[(size_t)sA * 128 + cbase];
      const float* rowB = &Hm[(size_t)sB * 128 + cbase];
      float4 hA0 = *(const float4*)rowA, hA1 = *(const float4*)(rowA + 4);
      float4 hB0 = *(const float4*)rowB, hB1 = *(const float4*)(rowB + 4);
      a0 += hA0.x * alA + hB0.x * alB; a1 += hA0.y * alA + hB0.y * alB;
      a2 += hA0.z * alA + hB0.z * alB; a3 += hA0.w * alA + hB0.w * alB;
      a4 += hA1.x * alA + hB1.x * alB; a5 += hA1.y * alA + hB1.y * alB;
      a6 += hA1.z * alA + hB1.z * alB; a7 += hA1.w * alA + hB1.w * alB;
    }
  }
  a0 += __shfl_xor(a0, 16); a0 += __shfl_xor(a0, 32);
  a1 += __shfl_xor(a1, 16); a1 += __shfl_xor(a1, 32);
  a2 += __shfl_xor(a2, 16); a2 += __shfl_xor(a2, 32);
  a3 += __shfl_xor(a3, 16); a3 += __shfl_xor(a3, 32);
  a4 += __shfl_xor(a4, 16); a4 += __shfl_xor(a4, 32);
  a5 += __shfl_xor(a5, 16); a5 += __shfl_xor(a5, 32);
  a6 += __shfl_xor(a6, 16); a6 += __shfl_xor(a6, 32);
  a7 += __shfl_xor(a7, 16); a7 += __shfl_xor(a7, 32);
  if (grp == 0) {
    float4 b0 = *(const float4*)&bias[cbase];
    float4 b1 = *(const float4*)&bias[cbase + 4];
    float4 o0, o1;
    o0.x = fmaxf(a0 + b0.x, 0.f); o0.y = fmaxf(a1 + b0.y, 0.f);
    o0.z = fmaxf(a2 + b0.z, 0.f); o0.w = fmaxf(a3 + b0.w, 0.f);
    o1.x = fmaxf(a4 + b1.x, 0.f); o1.y = fmaxf(a5 + b1.y, 0.f);
    o1.z = fmaxf(a6 + b1.z, 0.f); o1.w = fmaxf(a7 + b1.w, 0.f);
    *(float4*)&out[(size_t)n * 128 + cbase] = o0;
    *(float4*)&out[(size_t)n * 128 + cbase + 4] = o1;
  }
}

// ---------------- layer-2 small aggregation (H=1,C=64): node per 16-lane group ----------------
__global__ __launch_bounds__(256) void agg2_small_k(const int* __restrict__ rowptr,
                                                    const int* __restrict__ srcs,
                                                    const float* __restrict__ as,
                                                    const float* __restrict__ ad,
                                                    const float* __restrict__ Hm,
                                                    const float* __restrict__ bias,
                                                    float* __restrict__ out,
                                                    const int* __restrict__ small_list,
                                                    const int* __restrict__ lcnt) {
  __shared__ float al_sm[16][17];
  __shared__ int   sr_sm[16][16];
  int g  = threadIdx.x >> 4;
  int gl = threadIdx.x & 15;
  int gidx = blockIdx.x * 16 + g;
  if (gidx >= lcnt[0]) return;
  int n = small_list[gidx];
  int r0 = rowptr[n];
  int deg = rowptr[n + 1] - r0;
  float adn = ad[n];

  float e = -INFINITY;
  int s = 0;
  if (gl < deg) { s = srcs[r0 + gl]; e = leaky(as[s] + adn); }
  sr_sm[g][gl] = s;
  float m = e;
  #pragma unroll
  for (int off = 8; off > 0; off >>= 1) m = fmaxf(m, __shfl_xor(m, off, 16));
  float sc = (gl < deg) ? __expf(e - m) : 0.f;
  float ssum = sc;
  #pragma unroll
  for (int off = 8; off > 0; off >>= 1) ssum += __shfl_xor(ssum, off, 16);
  al_sm[g][gl] = sc / ssum;

  int cbase = gl * 4;
  float a0 = 0.f, a1 = 0.f, a2 = 0.f, a3 = 0.f;
  for (int j = 0; j < deg; j += 4) {
    #pragma unroll
    for (int u = 0; u < 4; ++u) {
      int idx = j + u;
      bool vU = idx < deg;
      int jj = vU ? idx : 0;
      int   sU  = sr_sm[g][jj];
      float alU = vU ? al_sm[g][jj] : 0.f;
      float4 hv = *(const float4*)&Hm[(size_t)sU * 64 + cbase];
      a0 += hv.x * alU; a1 += hv.y * alU; a2 += hv.z * alU; a3 += hv.w * alU;
    }
  }
  float4 bv = *(const float4*)&bias[cbase];
  float4 o;
  o.x = a0 + bv.x; o.y = a1 + bv.y; o.z = a2 + bv.z; o.w = a3 + bv.w;
  *(float4*)&out[(size_t)n * 64 + cbase] = o;
}

// ---------------- layer-2 big aggregation: node per wave ----------------
__global__ __launch_bounds__(256) void agg2_big_k(const int* __restrict__ rowptr,
                                                  const int* __restrict__ srcs,
                                                  const float* __restrict__ as,
                                                  const float* __restrict__ ad,
                                                  const float* __restrict__ Hm,
                                                  const float* __restrict__ bias,
                                                  float* __restrict__ out,
                                                  const int* __restrict__ big_list,
                                                  const int* __restrict__ lcnt) {
  __shared__ float al_sm[4][64];
  __shared__ int   sr_sm[4][64];
  int wv = threadIdx.x >> 6, lane = threadIdx.x & 63;
  int widx = blockIdx.x * 4 + wv;
  if (widx >= lcnt[1]) return;
  int n = big_list[widx];
  int r0 = rowptr[n], r1 = rowptr[n + 1];
  int deg = r1 - r0;
  int grp = lane >> 4, gl = lane & 15;
  int cbase = gl * 4;
  float adn = ad[n];

  float a0 = 0.f, a1 = 0.f, a2 = 0.f, a3 = 0.f;

  if (deg <= 64) {
    float e = -INFINITY;
    int s = 0;
    if (lane < deg) { s = srcs[r0 + lane]; e = leaky(as[s] + adn); }
    sr_sm[wv][lane] = s;
    float m = e;
    #pragma unroll
    for (int off = 32; off > 0; off >>= 1) m = fmaxf(m, __shfl_xor(m, off));
    float sc = (lane < deg) ? __expf(e - m) : 0.f;
    float ssum = sc;
    #pragma unroll
    for (int off = 32; off > 0; off >>= 1) ssum += __shfl_xor(ssum, off);
    al_sm[wv][lane] = sc / ssum;

    for (int base = 0; base < deg; base += 16) {
      #pragma unroll
      for (int u = 0; u < 4; ++u) {
        int idx = base + grp * 4 + u;
        bool vU = idx < deg;
        int jj = vU ? idx : 0;
        int   sU  = sr_sm[wv][jj];
        float alU = vU ? al_sm[wv][jj] : 0.f;
        float4 hv = *(const float4*)&Hm[(size_t)sU * 64 + cbase];
        a0 += hv.x * alU; a1 += hv.y * alU; a2 += hv.z * alU; a3 += hv.w * alU;
      }
    }
  } else {
    float mh = -INFINITY;
    for (int r = r0 + lane; r < r1; r += 64)
      mh = fmaxf(mh, leaky(as[srcs[r]] + adn));
    #pragma unroll
    for (int off = 32; off > 0; off >>= 1) mh = fmaxf(mh, __shfl_xor(mh, off));
    float ssum = 0.f;
    for (int r = r0 + lane; r < r1; r += 64)
      ssum += __expf(leaky(as[srcs[r]] + adn) - mh);
    #pragma unroll
    for (int off = 32; off > 0; off >>= 1) ssum += __shfl_xor(ssum, off);
    float inv = 1.f / ssum;
    for (int r = r0; r < r1; r += 8) {
      int rA = r + grp, rB = rA + 4;
      bool vA = rA < r1, vB = rB < r1;
      int sA = srcs[vA ? rA : r0];
      int sB = srcs[vB ? rB : r0];
      float alA = vA ? (__expf(leaky(as[sA] + adn) - mh) * inv) : 0.f;
      float alB = vB ? (__expf(leaky(as[sB] + adn) - mh) * inv) : 0.f;
      float4 hA = *(const float4*)&Hm[(size_t)sA * 64 + cbase];
      float4 hB = *(const float4*)&Hm[(size_t)sB * 64 + cbase];
      a0 += hA.x * alA + hB.x * alB; a1 += hA.y * alA + hB.y * alB;
      a2 += hA.z * alA + hB.z * alB; a3 += hA.w * alA + hB.w * alB;
    }
  }
  a0 += __shfl_xor(a0, 16); a0 += __shfl_xor(a0, 32);
  a1 += __shfl_xor(a1, 16); a1 += __shfl_xor(a1, 32);
  a2 += __shfl_xor(a2, 16); a2 += __shfl_xor(a2, 32);
  a3 += __shfl_xor(a3, 16); a3 += __shfl_xor(a3, 32);
  if (grp == 0) {
    float4 bv = *(const float4*)&bias[cbase];
    float4 o;
    o.x = a0 + bv.x; o.y = a1 + bv.y; o.z = a2 + bv.z; o.w = a3 + bv.w;
    *(float4*)&out[(size_t)n * 64 + cbase] = o;
  }
}

extern "C" void kernel_launch(void* const* d_in, const int* in_sizes, int n_in,
                              void* d_out, int out_size, void* d_ws, size_t ws_size,
                              hipStream_t stream) {
  const float* x   = (const float*)d_in[0];
  const int*   ei  = (const int*)d_in[1];
  // d_in[2] edge_weight: unused by GATConv (edge_dim unset)
  const float* W1  = (const float*)d_in[3];
  const float* aS1 = (const float*)d_in[4];
  const float* aD1 = (const float*)d_in[5];
  const float* b1  = (const float*)d_in[6];
  const float* W2  = (const float*)d_in[7];
  const float* aS2 = (const float*)d_in[8];
  const float* aD2 = (const float*)d_in[9];
  const float* b2  = (const float*)d_in[10];

  const int N  = in_sizes[0] / 128;
  const int E  = in_sizes[2];
  const int ET = E + N;

  float* ws   = (float*)d_ws;
  float* h1   = ws;                           // N*128 (reused as h2 after layer 1)
  float* out1 = h1   + (size_t)N * 128;       // N*128
  float* as1  = out1 + (size_t)N * 128;       // 4N
  float* ad1  = as1  + (size_t)4 * N;         // 4N
  float* as2  = ad1  + (size_t)4 * N;         // N
  float* ad2  = as2  + (size_t)N;             // N
  int*   cnt    = (int*)(ad2 + (size_t)N);    // N
  int*   lcnt   = cnt    + N;                 // 2 (zeroed with cnt)
  int*   rowptr = lcnt   + 2;                 // N+1
  int*   cursor = rowptr + N + 1;             // N
  int*   rowtmp = cursor + N;                 // N
  int*   bsum   = rowtmp + N;                 // 256
  int*   small_list = bsum + 256;             // N
  int*   big_list   = small_list + N;         // N
  int*   srcs   = big_list + N;               // ET
  float* h2   = h1;                           // alias (h1 dead after agg1)
  float* out  = (float*)d_out;                // N*64

  const int eb  = (ET + 255) / 256;
  const int nb  = (N + 255) / 256;            // scan blocks (nb <= 256 required)
  const int gb  = (N + 63) / 64;              // gemm blocks
  const int sb  = (N + 15) / 16;              // small-agg blocks (worst case)
  const int bb  = (N + 3) / 4;                // big-agg blocks (worst case)

  // ---- CSR build (graph shared by both layers) ----
  hipMemsetAsync(cnt, 0, (size_t)(N + 2) * sizeof(int), stream);
  hist_k<<<eb, 256, 0, stream>>>(ei, E, ET, cnt);
  scan1_k<<<nb, 256, 0, stream>>>(cnt, rowtmp, bsum, N);
  scan2_k<<<1, 256, 0, stream>>>(bsum, nb);
  scan3_k<<<nb, 256, 0, stream>>>(rowtmp, bsum, cnt, rowptr, cursor,
                                  small_list, big_list, lcnt, N, ET);
  scatter_k<<<eb, 256, 0, stream>>>(ei, E, ET, cursor, srcs);

  // ---- layer 1 ----
  gemm1_k<<<gb, 256, 0, stream>>>(x, W1, aS1, aD1, h1, as1, ad1, N);
  agg1_small_k<<<sb, 256, 0, stream>>>(rowptr, srcs, as1, ad1, h1, b1, out1,
                                       small_list, lcnt);
  agg1_big_k<<<bb, 256, 0, stream>>>(rowptr, srcs, as1, ad1, h1, b1, out1,
                                     big_list, lcnt);

  // ---- layer 2 ----
  gemm2_k<<<gb, 256, 0, stream>>>(out1, W2, aS2, aD2, h2, as2, ad2, N);
  agg2_small_k<<<sb, 256, 0, stream>>>(rowptr, srcs, as2, ad2, h2, b2, out,
                                       small_list, lcnt);
  agg2_big_k<<<bb, 256, 0, stream>>>(rowptr, srcs, as2, ad2, h2, b2, out,
                                     big_list, lcnt);
}

// Round 8
// 365.489 us; speedup vs baseline: 2.0137x; 2.0137x over previous
//
#include <hip/hip_runtime.h>
#include <math.h>

// GAT (2 layers) on MI355X — CSR + degree-bucketed aggregation.
// small (deg<=16): one node per 16-lane group, 4 nodes/wave, LDS alpha/src.
// big (deg>16):    one node per wave; deg<=64 lane-per-edge softmax + LDS
//                  alpha/src; deg>64 strided fallback.
// scan3 builds bucket lists with WAVE-AGGREGATED atomics (1 atomic/wave/list,
// not 1/thread — per-thread contended atomicAdd on 2 addresses cost 390 µs).

#define NEG_SLOPE 0.2f

__device__ __forceinline__ float leaky(float v) { return v > 0.f ? v : NEG_SLOPE * v; }

// ---------------- CSR build ----------------
__global__ __launch_bounds__(256) void hist_k(const int* __restrict__ ei, int E, int ET,
                                              int* __restrict__ cnt) {
  int e = blockIdx.x * 256 + threadIdx.x;
  if (e >= ET) return;
  int d = (e < E) ? ei[E + e] : (e - E);
  atomicAdd(&cnt[d], 1);
}

__global__ __launch_bounds__(256) void scan1_k(const int* __restrict__ cnt,
                                               int* __restrict__ rowtmp,
                                               int* __restrict__ bsum, int N) {
  int i = blockIdx.x * 256 + threadIdx.x;
  int v = (i < N) ? cnt[i] : 0;
  __shared__ int sm[256];
  sm[threadIdx.x] = v;
  __syncthreads();
  #pragma unroll
  for (int off = 1; off < 256; off <<= 1) {
    int t = (threadIdx.x >= off) ? sm[threadIdx.x - off] : 0;
    __syncthreads();
    sm[threadIdx.x] += t;
    __syncthreads();
  }
  if (i < N) rowtmp[i] = sm[threadIdx.x] - v;
  if (threadIdx.x == 255) bsum[blockIdx.x] = sm[255];
}

__global__ __launch_bounds__(256) void scan2_k(int* __restrict__ bsum, int nb) {
  __shared__ int sm[256];
  int v = (threadIdx.x < nb) ? bsum[threadIdx.x] : 0;
  sm[threadIdx.x] = v;
  __syncthreads();
  #pragma unroll
  for (int off = 1; off < 256; off <<= 1) {
    int t = (threadIdx.x >= off) ? sm[threadIdx.x - off] : 0;
    __syncthreads();
    sm[threadIdx.x] += t;
    __syncthreads();
  }
  if (threadIdx.x < nb) bsum[threadIdx.x] = sm[threadIdx.x] - v;
}

// pass 3: rowptr/cursor + degree buckets (wave-aggregated list append)
__global__ __launch_bounds__(256) void scan3_k(const int* __restrict__ rowtmp,
                                               const int* __restrict__ bsum,
                                               const int* __restrict__ cnt,
                                               int* __restrict__ rowptr,
                                               int* __restrict__ cursor,
                                               int* __restrict__ small_list,
                                               int* __restrict__ big_list,
                                               int* __restrict__ lcnt,
                                               int N, int ET) {
  int i = blockIdx.x * 256 + threadIdx.x;
  int lane = threadIdx.x & 63;
  bool valid = (i < N);
  int deg = 0;
  if (valid) {
    int v = rowtmp[i] + bsum[blockIdx.x];
    rowptr[i] = v;
    cursor[i] = v;
    deg = cnt[i];
  }
  bool isSmall = valid && (deg <= 16);
  bool isBig   = valid && (deg > 16);

  unsigned long long ms = __ballot(isSmall);
  unsigned long long mb = __ballot(isBig);
  unsigned long long below = (lane == 0) ? 0ull : (~0ull >> (64 - lane));
  int baseS = 0, baseB = 0;
  if (lane == 0) {
    baseS = atomicAdd(&lcnt[0], __popcll(ms));
    baseB = atomicAdd(&lcnt[1], __popcll(mb));
  }
  baseS = __shfl(baseS, 0);
  baseB = __shfl(baseB, 0);
  if (isSmall) small_list[baseS + __popcll(ms & below)] = i;
  if (isBig)   big_list[baseB + __popcll(mb & below)]   = i;
  if (i == 0) rowptr[N] = ET;
}

__global__ __launch_bounds__(256) void scatter_k(const int* __restrict__ ei, int E, int ET,
                                                 int* __restrict__ cursor,
                                                 int* __restrict__ srcs) {
  int e = blockIdx.x * 256 + threadIdx.x;
  if (e >= ET) return;
  int s, d;
  if (e < E) { s = ei[e]; d = ei[E + e]; } else { s = d = e - E; }
  int pos = atomicAdd(&cursor[d], 1);
  srcs[pos] = s;
}

// ---------------- GEMM1 + alpha1 ----------------
__global__ __launch_bounds__(256) void gemm1_k(const float* __restrict__ X,
                                               const float* __restrict__ W,
                                               const float* __restrict__ aw_s,
                                               const float* __restrict__ aw_d,
                                               float* __restrict__ Hout,
                                               float* __restrict__ as,
                                               float* __restrict__ ad, int N) {
  __shared__ float wl[32 * 128];
  __shared__ float xt[32][72];
  int cl = threadIdx.x & 31, rg = threadIdx.x >> 5;
  int c4 = cl * 4;
  int n0 = blockIdx.x * 64;
  float acc[8][4] = {};
  const float4* X4 = (const float4*)X;
  const float4* W4 = (const float4*)W;
  for (int k0 = 0; k0 < 128; k0 += 32) {
    __syncthreads();
    for (int i = threadIdx.x; i < 1024; i += 256)
      ((float4*)wl)[i] = W4[k0 * 32 + i];
    for (int i = threadIdx.x; i < 512; i += 256) {
      int r = i >> 3, kk4 = (i & 7) * 4;
      int n = n0 + r;
      float4 xv = (n < N) ? X4[(size_t)n * 32 + (k0 >> 2) + (i & 7)]
                          : make_float4(0.f, 0.f, 0.f, 0.f);
      xt[kk4 + 0][r] = xv.x; xt[kk4 + 1][r] = xv.y;
      xt[kk4 + 2][r] = xv.z; xt[kk4 + 3][r] = xv.w;
    }
    __syncthreads();
    #pragma unroll 8
    for (int kk = 0; kk < 32; ++kk) {
      float4 w4 = *(const float4*)&wl[kk * 128 + c4];
      float4 xa = *(const float4*)&xt[kk][rg * 8];
      float4 xb = *(const float4*)&xt[kk][rg * 8 + 4];
      float xr[8] = {xa.x, xa.y, xa.z, xa.w, xb.x, xb.y, xb.z, xb.w};
      #pragma unroll
      for (int j = 0; j < 8; ++j) {
        acc[j][0] += xr[j] * w4.x; acc[j][1] += xr[j] * w4.y;
        acc[j][2] += xr[j] * w4.z; acc[j][3] += xr[j] * w4.w;
      }
    }
  }
  float4 aws = *(const float4*)&aw_s[c4];
  float4 awd = *(const float4*)&aw_d[c4];
  #pragma unroll
  for (int j = 0; j < 8; ++j) {
    int n = n0 + rg * 8 + j;
    float ps = acc[j][0] * aws.x + acc[j][1] * aws.y + acc[j][2] * aws.z + acc[j][3] * aws.w;
    float pd = acc[j][0] * awd.x + acc[j][1] * awd.y + acc[j][2] * awd.z + acc[j][3] * awd.w;
    ps += __shfl_xor(ps, 1); ps += __shfl_xor(ps, 2); ps += __shfl_xor(ps, 4);
    pd += __shfl_xor(pd, 1); pd += __shfl_xor(pd, 2); pd += __shfl_xor(pd, 4);
    if (n < N) {
      *(float4*)&Hout[(size_t)n * 128 + c4] =
          make_float4(acc[j][0], acc[j][1], acc[j][2], acc[j][3]);
      if ((cl & 7) == 0) {
        as[n * 4 + (cl >> 3)] = ps;
        ad[n * 4 + (cl >> 3)] = pd;
      }
    }
  }
}

// ---------------- GEMM2 + alpha2 ----------------
__global__ __launch_bounds__(256) void gemm2_k(const float* __restrict__ X,
                                               const float* __restrict__ W,
                                               const float* __restrict__ aw_s,
                                               const float* __restrict__ aw_d,
                                               float* __restrict__ Hout,
                                               float* __restrict__ as,
                                               float* __restrict__ ad, int N) {
  __shared__ float wl[32 * 64];
  __shared__ float xt[32][72];
  int cl = threadIdx.x & 15, rg = threadIdx.x >> 4;
  int c4 = cl * 4;
  int n0 = blockIdx.x * 64;
  float acc[4][4] = {};
  const float4* X4 = (const float4*)X;
  const float4* W4 = (const float4*)W;
  for (int k0 = 0; k0 < 128; k0 += 32) {
    __syncthreads();
    for (int i = threadIdx.x; i < 512; i += 256)
      ((float4*)wl)[i] = W4[k0 * 16 + i];
    for (int i = threadIdx.x; i < 512; i += 256) {
      int r = i >> 3, kk4 = (i & 7) * 4;
      int n = n0 + r;
      float4 xv = (n < N) ? X4[(size_t)n * 32 + (k0 >> 2) + (i & 7)]
                          : make_float4(0.f, 0.f, 0.f, 0.f);
      xt[kk4 + 0][r] = xv.x; xt[kk4 + 1][r] = xv.y;
      xt[kk4 + 2][r] = xv.z; xt[kk4 + 3][r] = xv.w;
    }
    __syncthreads();
    #pragma unroll 8
    for (int kk = 0; kk < 32; ++kk) {
      float4 w4 = *(const float4*)&wl[kk * 64 + c4];
      float4 xa = *(const float4*)&xt[kk][rg * 4];
      float xr[4] = {xa.x, xa.y, xa.z, xa.w};
      #pragma unroll
      for (int j = 0; j < 4; ++j) {
        acc[j][0] += xr[j] * w4.x; acc[j][1] += xr[j] * w4.y;
        acc[j][2] += xr[j] * w4.z; acc[j][3] += xr[j] * w4.w;
      }
    }
  }
  float4 aws = *(const float4*)&aw_s[c4];
  float4 awd = *(const float4*)&aw_d[c4];
  #pragma unroll
  for (int j = 0; j < 4; ++j) {
    int n = n0 + rg * 4 + j;
    float ps = acc[j][0] * aws.x + acc[j][1] * aws.y + acc[j][2] * aws.z + acc[j][3] * aws.w;
    float pd = acc[j][0] * awd.x + acc[j][1] * awd.y + acc[j][2] * awd.z + acc[j][3] * awd.w;
    ps += __shfl_xor(ps, 1); ps += __shfl_xor(ps, 2);
    ps += __shfl_xor(ps, 4); ps += __shfl_xor(ps, 8);
    pd += __shfl_xor(pd, 1); pd += __shfl_xor(pd, 2);
    pd += __shfl_xor(pd, 4); pd += __shfl_xor(pd, 8);
    if (n < N) {
      *(float4*)&Hout[(size_t)n * 64 + c4] =
          make_float4(acc[j][0], acc[j][1], acc[j][2], acc[j][3]);
      if (cl == 0) { as[n] = ps; ad[n] = pd; }
    }
  }
}

// ---------------- layer-1 small aggregation: node per 16-lane group ----------------
__global__ __launch_bounds__(256) void agg1_small_k(const int* __restrict__ rowptr,
                                                    const int* __restrict__ srcs,
                                                    const float* __restrict__ as,
                                                    const float* __restrict__ ad,
                                                    const float* __restrict__ Hm,
                                                    const float* __restrict__ bias,
                                                    float* __restrict__ out,
                                                    const int* __restrict__ small_list,
                                                    const int* __restrict__ lcnt) {
  __shared__ float al_sm[16][17][4];
  __shared__ int   sr_sm[16][16];
  int g  = threadIdx.x >> 4;
  int gl = threadIdx.x & 15;
  int gidx = blockIdx.x * 16 + g;
  if (gidx >= lcnt[0]) return;
  int n = small_list[gidx];
  int r0 = rowptr[n];
  int deg = rowptr[n + 1] - r0;        // 1..16
  float4 adn = *(const float4*)&ad[n * 4];

  float e0 = -INFINITY, e1 = -INFINITY, e2 = -INFINITY, e3 = -INFINITY;
  int s = 0;
  if (gl < deg) {
    s = srcs[r0 + gl];
    float4 av = *(const float4*)&as[s * 4];
    e0 = leaky(av.x + adn.x); e1 = leaky(av.y + adn.y);
    e2 = leaky(av.z + adn.z); e3 = leaky(av.w + adn.w);
  }
  sr_sm[g][gl] = s;
  float m0 = e0, m1 = e1, m2 = e2, m3 = e3;
  #pragma unroll
  for (int off = 8; off > 0; off >>= 1) {
    m0 = fmaxf(m0, __shfl_xor(m0, off, 16)); m1 = fmaxf(m1, __shfl_xor(m1, off, 16));
    m2 = fmaxf(m2, __shfl_xor(m2, off, 16)); m3 = fmaxf(m3, __shfl_xor(m3, off, 16));
  }
  float sc0 = (gl < deg) ? __expf(e0 - m0) : 0.f;
  float sc1 = (gl < deg) ? __expf(e1 - m1) : 0.f;
  float sc2 = (gl < deg) ? __expf(e2 - m2) : 0.f;
  float sc3 = (gl < deg) ? __expf(e3 - m3) : 0.f;
  float s0 = sc0, s1 = sc1, s2 = sc2, s3 = sc3;
  #pragma unroll
  for (int off = 8; off > 0; off >>= 1) {
    s0 += __shfl_xor(s0, off, 16); s1 += __shfl_xor(s1, off, 16);
    s2 += __shfl_xor(s2, off, 16); s3 += __shfl_xor(s3, off, 16);
  }
  *(float4*)&al_sm[g][gl][0] =
      make_float4(sc0 / s0, sc1 / s1, sc2 / s2, sc3 / s3);

  int h = gl >> 2;
  int cbase = gl * 8;
  float a0 = 0.f, a1 = 0.f, a2 = 0.f, a3 = 0.f,
        a4 = 0.f, a5 = 0.f, a6 = 0.f, a7 = 0.f;
  for (int j = 0; j < deg; j += 4) {
    #pragma unroll
    for (int u = 0; u < 4; ++u) {
      int idx = j + u;
      bool vU = idx < deg;
      int jj = vU ? idx : 0;
      int   sU  = sr_sm[g][jj];
      float alU = vU ? al_sm[g][jj][h] : 0.f;
      const float* row = &Hm[(size_t)sU * 128 + cbase];
      float4 h0 = *(const float4*)row;
      float4 h1 = *(const float4*)(row + 4);
      a0 += h0.x * alU; a1 += h0.y * alU; a2 += h0.z * alU; a3 += h0.w * alU;
      a4 += h1.x * alU; a5 += h1.y * alU; a6 += h1.z * alU; a7 += h1.w * alU;
    }
  }
  float4 b0 = *(const float4*)&bias[cbase];
  float4 b1 = *(const float4*)&bias[cbase + 4];
  float4 o0, o1;
  o0.x = fmaxf(a0 + b0.x, 0.f); o0.y = fmaxf(a1 + b0.y, 0.f);
  o0.z = fmaxf(a2 + b0.z, 0.f); o0.w = fmaxf(a3 + b0.w, 0.f);
  o1.x = fmaxf(a4 + b1.x, 0.f); o1.y = fmaxf(a5 + b1.y, 0.f);
  o1.z = fmaxf(a6 + b1.z, 0.f); o1.w = fmaxf(a7 + b1.w, 0.f);
  *(float4*)&out[(size_t)n * 128 + cbase] = o0;
  *(float4*)&out[(size_t)n * 128 + cbase + 4] = o1;
}

// ---------------- layer-1 big aggregation: node per wave ----------------
__global__ __launch_bounds__(256) void agg1_big_k(const int* __restrict__ rowptr,
                                                  const int* __restrict__ srcs,
                                                  const float* __restrict__ as,
                                                  const float* __restrict__ ad,
                                                  const float* __restrict__ Hm,
                                                  const float* __restrict__ bias,
                                                  float* __restrict__ out,
                                                  const int* __restrict__ big_list,
                                                  const int* __restrict__ lcnt) {
  __shared__ float al_sm[4][64][4];
  __shared__ int   sr_sm[4][64];
  int wv = threadIdx.x >> 6, lane = threadIdx.x & 63;
  int widx = blockIdx.x * 4 + wv;
  if (widx >= lcnt[1]) return;
  int n = big_list[widx];
  int r0 = rowptr[n], r1 = rowptr[n + 1];
  int deg = r1 - r0;
  int grp = lane >> 4, gl = lane & 15, h = gl >> 2;
  int cbase = gl * 8;
  float4 adn = *(const float4*)&ad[n * 4];

  float a0 = 0.f, a1 = 0.f, a2 = 0.f, a3 = 0.f,
        a4 = 0.f, a5 = 0.f, a6 = 0.f, a7 = 0.f;

  if (deg <= 64) {
    float e0 = -INFINITY, e1 = -INFINITY, e2 = -INFINITY, e3 = -INFINITY;
    int s = 0;
    if (lane < deg) {
      s = srcs[r0 + lane];
      float4 av = *(const float4*)&as[s * 4];
      e0 = leaky(av.x + adn.x); e1 = leaky(av.y + adn.y);
      e2 = leaky(av.z + adn.z); e3 = leaky(av.w + adn.w);
    }
    sr_sm[wv][lane] = s;
    float m0 = e0, m1 = e1, m2 = e2, m3 = e3;
    #pragma unroll
    for (int off = 32; off > 0; off >>= 1) {
      m0 = fmaxf(m0, __shfl_xor(m0, off)); m1 = fmaxf(m1, __shfl_xor(m1, off));
      m2 = fmaxf(m2, __shfl_xor(m2, off)); m3 = fmaxf(m3, __shfl_xor(m3, off));
    }
    float sc0 = (lane < deg) ? __expf(e0 - m0) : 0.f;
    float sc1 = (lane < deg) ? __expf(e1 - m1) : 0.f;
    float sc2 = (lane < deg) ? __expf(e2 - m2) : 0.f;
    float sc3 = (lane < deg) ? __expf(e3 - m3) : 0.f;
    float s0 = sc0, s1 = sc1, s2 = sc2, s3 = sc3;
    #pragma unroll
    for (int off = 32; off > 0; off >>= 1) {
      s0 += __shfl_xor(s0, off); s1 += __shfl_xor(s1, off);
      s2 += __shfl_xor(s2, off); s3 += __shfl_xor(s3, off);
    }
    *(float4*)&al_sm[wv][lane][0] =
        make_float4(sc0 / s0, sc1 / s1, sc2 / s2, sc3 / s3);

    for (int base = 0; base < deg; base += 16) {
      #pragma unroll
      for (int u = 0; u < 4; ++u) {
        int idx = base + grp * 4 + u;
        bool vU = idx < deg;
        int jj = vU ? idx : 0;
        int   sU  = sr_sm[wv][jj];
        float alU = vU ? al_sm[wv][jj][h] : 0.f;
        const float* row = &Hm[(size_t)sU * 128 + cbase];
        float4 h0 = *(const float4*)row;
        float4 h1 = *(const float4*)(row + 4);
        a0 += h0.x * alU; a1 += h0.y * alU; a2 += h0.z * alU; a3 += h0.w * alU;
        a4 += h1.x * alU; a5 += h1.y * alU; a6 += h1.z * alU; a7 += h1.w * alU;
      }
    }
  } else {
    float m0 = -INFINITY, m1 = -INFINITY, m2 = -INFINITY, m3 = -INFINITY;
    for (int r = r0 + lane; r < r1; r += 64) {
      int s = srcs[r];
      float4 av = *(const float4*)&as[s * 4];
      m0 = fmaxf(m0, leaky(av.x + adn.x)); m1 = fmaxf(m1, leaky(av.y + adn.y));
      m2 = fmaxf(m2, leaky(av.z + adn.z)); m3 = fmaxf(m3, leaky(av.w + adn.w));
    }
    #pragma unroll
    for (int off = 32; off > 0; off >>= 1) {
      m0 = fmaxf(m0, __shfl_xor(m0, off)); m1 = fmaxf(m1, __shfl_xor(m1, off));
      m2 = fmaxf(m2, __shfl_xor(m2, off)); m3 = fmaxf(m3, __shfl_xor(m3, off));
    }
    float s0 = 0.f, s1 = 0.f, s2 = 0.f, s3 = 0.f;
    for (int r = r0 + lane; r < r1; r += 64) {
      int s = srcs[r];
      float4 av = *(const float4*)&as[s * 4];
      s0 += __expf(leaky(av.x + adn.x) - m0); s1 += __expf(leaky(av.y + adn.y) - m1);
      s2 += __expf(leaky(av.z + adn.z) - m2); s3 += __expf(leaky(av.w + adn.w) - m3);
    }
    #pragma unroll
    for (int off = 32; off > 0; off >>= 1) {
      s0 += __shfl_xor(s0, off); s1 += __shfl_xor(s1, off);
      s2 += __shfl_xor(s2, off); s3 += __shfl_xor(s3, off);
    }
    float mhh = (h == 0) ? m0 : (h == 1) ? m1 : (h == 2) ? m2 : m3;
    float inv = 1.f / ((h == 0) ? s0 : (h == 1) ? s1 : (h == 2) ? s2 : s3);
    float adh = (h == 0) ? adn.x : (h == 1) ? adn.y : (h == 2) ? adn.z : adn.w;
    for (int r = r0; r < r1; r += 8) {
      int rA = r + grp, rB = rA + 4;
      bool vA = rA < r1, vB = rB < r1;
      int sA = srcs[vA ? rA : r0];
      int sB = srcs[vB ? rB : r0];
      float avA = as[sA * 4 + h], avB = as[sB * 4 + h];
      float alA = vA ? (__expf(leaky(avA + adh) - mhh) * inv) : 0.f;
      float alB = vB ? (__expf(leaky(avB + adh) - mhh) * inv) : 0.f;
      const float* rowA = &Hm[(size_t)sA * 128 + cbase];
      const float* rowB = &Hm[(size_t)sB * 128 + cbase];
      float4 hA0 = *(const float4*)rowA, hA1 = *(const float4*)(rowA + 4);
      float4 hB0 = *(const float4*)rowB, hB1 = *(const float4*)(rowB + 4);
      a0 += hA0.x * alA + hB0.x * alB; a1 += hA0.y * alA + hB0.y * alB;
      a2 += hA0.z * alA + hB0.z * alB; a3 += hA0.w * alA + hB0.w * alB;
      a4 += hA1.x * alA + hB1.x * alB; a5 += hA1.y * alA + hB1.y * alB;
      a6 += hA1.z * alA + hB1.z * alB; a7 += hA1.w * alA + hB1.w * alB;
    }
  }
  a0 += __shfl_xor(a0, 16); a0 += __shfl_xor(a0, 32);
  a1 += __shfl_xor(a1, 16); a1 += __shfl_xor(a1, 32);
  a2 += __shfl_xor(a2, 16); a2 += __shfl_xor(a2, 32);
  a3 += __shfl_xor(a3, 16); a3 += __shfl_xor(a3, 32);
  a4 += __shfl_xor(a4, 16); a4 += __shfl_xor(a4, 32);
  a5 += __shfl_xor(a5, 16); a5 += __shfl_xor(a5, 32);
  a6 += __shfl_xor(a6, 16); a6 += __shfl_xor(a6, 32);
  a7 += __shfl_xor(a7, 16); a7 += __shfl_xor(a7, 32);
  if (grp == 0) {
    float4 b0 = *(const float4*)&bias[cbase];
    float4 b1 = *(const float4*)&bias[cbase + 4];
    float4 o0, o1;
    o0.x = fmaxf(a0 + b0.x, 0.f); o0.y = fmaxf(a1 + b0.y, 0.f);
    o0.z = fmaxf(a2 + b0.z, 0.f); o0.w = fmaxf(a3 + b0.w, 0.f);
    o1.x = fmaxf(a4 + b1.x, 0.f); o1.y = fmaxf(a5 + b1.y, 0.f);
    o1.z = fmaxf(a6 + b1.z, 0.f); o1.w = fmaxf(a7 + b1.w, 0.f);
    *(float4*)&out[(size_t)n * 128 + cbase] = o0;
    *(float4*)&out[(size_t)n * 128 + cbase + 4] = o1;
  }
}

// ---------------- layer-2 small aggregation (H=1,C=64) ----------------
__global__ __launch_bounds__(256) void agg2_small_k(const int* __restrict__ rowptr,
                                                    const int* __restrict__ srcs,
                                                    const float* __restrict__ as,
                                                    const float* __restrict__ ad,
                                                    const float* __restrict__ Hm,
                                                    const float* __restrict__ bias,
                                                    float* __restrict__ out,
                                                    const int* __restrict__ small_list,
                                                    const int* __restrict__ lcnt) {
  __shared__ float al_sm[16][17];
  __shared__ int   sr_sm[16][16];
  int g  = threadIdx.x >> 4;
  int gl = threadIdx.x & 15;
  int gidx = blockIdx.x * 16 + g;
  if (gidx >= lcnt[0]) return;
  int n = small_list[gidx];
  int r0 = rowptr[n];
  int deg = rowptr[n + 1] - r0;
  float adn = ad[n];

  float e = -INFINITY;
  int s = 0;
  if (gl < deg) { s = srcs[r0 + gl]; e = leaky(as[s] + adn); }
  sr_sm[g][gl] = s;
  float m = e;
  #pragma unroll
  for (int off = 8; off > 0; off >>= 1) m = fmaxf(m, __shfl_xor(m, off, 16));
  float sc = (gl < deg) ? __expf(e - m) : 0.f;
  float ssum = sc;
  #pragma unroll
  for (int off = 8; off > 0; off >>= 1) ssum += __shfl_xor(ssum, off, 16);
  al_sm[g][gl] = sc / ssum;

  int cbase = gl * 4;
  float a0 = 0.f, a1 = 0.f, a2 = 0.f, a3 = 0.f;
  for (int j = 0; j < deg; j += 4) {
    #pragma unroll
    for (int u = 0; u < 4; ++u) {
      int idx = j + u;
      bool vU = idx < deg;
      int jj = vU ? idx : 0;
      int   sU  = sr_sm[g][jj];
      float alU = vU ? al_sm[g][jj] : 0.f;
      float4 hv = *(const float4*)&Hm[(size_t)sU * 64 + cbase];
      a0 += hv.x * alU; a1 += hv.y * alU; a2 += hv.z * alU; a3 += hv.w * alU;
    }
  }
  float4 bv = *(const float4*)&bias[cbase];
  float4 o;
  o.x = a0 + bv.x; o.y = a1 + bv.y; o.z = a2 + bv.z; o.w = a3 + bv.w;
  *(float4*)&out[(size_t)n * 64 + cbase] = o;
}

// ---------------- layer-2 big aggregation: node per wave ----------------
__global__ __launch_bounds__(256) void agg2_big_k(const int* __restrict__ rowptr,
                                                  const int* __restrict__ srcs,
                                                  const float* __restrict__ as,
                                                  const float* __restrict__ ad,
                                                  const float* __restrict__ Hm,
                                                  const float* __restrict__ bias,
                                                  float* __restrict__ out,
                                                  const int* __restrict__ big_list,
                                                  const int* __restrict__ lcnt) {
  __shared__ float al_sm[4][64];
  __shared__ int   sr_sm[4][64];
  int wv = threadIdx.x >> 6, lane = threadIdx.x & 63;
  int widx = blockIdx.x * 4 + wv;
  if (widx >= lcnt[1]) return;
  int n = big_list[widx];
  int r0 = rowptr[n], r1 = rowptr[n + 1];
  int deg = r1 - r0;
  int grp = lane >> 4, gl = lane & 15;
  int cbase = gl * 4;
  float adn = ad[n];

  float a0 = 0.f, a1 = 0.f, a2 = 0.f, a3 = 0.f;

  if (deg <= 64) {
    float e = -INFINITY;
    int s = 0;
    if (lane < deg) { s = srcs[r0 + lane]; e = leaky(as[s] + adn); }
    sr_sm[wv][lane] = s;
    float m = e;
    #pragma unroll
    for (int off = 32; off > 0; off >>= 1) m = fmaxf(m, __shfl_xor(m, off));
    float sc = (lane < deg) ? __expf(e - m) : 0.f;
    float ssum = sc;
    #pragma unroll
    for (int off = 32; off > 0; off >>= 1) ssum += __shfl_xor(ssum, off);
    al_sm[wv][lane] = sc / ssum;

    for (int base = 0; base < deg; base += 16) {
      #pragma unroll
      for (int u = 0; u < 4; ++u) {
        int idx = base + grp * 4 + u;
        bool vU = idx < deg;
        int jj = vU ? idx : 0;
        int   sU  = sr_sm[wv][jj];
        float alU = vU ? al_sm[wv][jj] : 0.f;
        float4 hv = *(const float4*)&Hm[(size_t)sU * 64 + cbase];
        a0 += hv.x * alU; a1 += hv.y * alU; a2 += hv.z * alU; a3 += hv.w * alU;
      }
    }
  } else {
    float mh = -INFINITY;
    for (int r = r0 + lane; r < r1; r += 64)
      mh = fmaxf(mh, leaky(as[srcs[r]] + adn));
    #pragma unroll
    for (int off = 32; off > 0; off >>= 1) mh = fmaxf(mh, __shfl_xor(mh, off));
    float ssum = 0.f;
    for (int r = r0 + lane; r < r1; r += 64)
      ssum += __expf(leaky(as[srcs[r]] + adn) - mh);
    #pragma unroll
    for (int off = 32; off > 0; off >>= 1) ssum += __shfl_xor(ssum, off);
    float inv = 1.f / ssum;
    for (int r = r0; r < r1; r += 8) {
      int rA = r + grp, rB = rA + 4;
      bool vA = rA < r1, vB = rB < r1;
      int sA = srcs[vA ? rA : r0];
      int sB = srcs[vB ? rB : r0];
      float alA = vA ? (__expf(leaky(as[sA] + adn) - mh) * inv) : 0.f;
      float alB = vB ? (__expf(leaky(as[sB] + adn) - mh) * inv) : 0.f;
      float4 hA = *(const float4*)&Hm[(size_t)sA * 64 + cbase];
      float4 hB = *(const float4*)&Hm[(size_t)sB * 64 + cbase];
      a0 += hA.x * alA + hB.x * alB; a1 += hA.y * alA + hB.y * alB;
      a2 += hA.z * alA + hB.z * alB; a3 += hA.w * alA + hB.w * alB;
    }
  }
  a0 += __shfl_xor(a0, 16); a0 += __shfl_xor(a0, 32);
  a1 += __shfl_xor(a1, 16); a1 += __shfl_xor(a1, 32);
  a2 += __shfl_xor(a2, 16); a2 += __shfl_xor(a2, 32);
  a3 += __shfl_xor(a3, 16); a3 += __shfl_xor(a3, 32);
  if (grp == 0) {
    float4 bv = *(const float4*)&bias[cbase];
    float4 o;
    o.x = a0 + bv.x; o.y = a1 + bv.y; o.z = a2 + bv.z; o.w = a3 + bv.w;
    *(float4*)&out[(size_t)n * 64 + cbase] = o;
  }
}

extern "C" void kernel_launch(void* const* d_in, const int* in_sizes, int n_in,
                              void* d_out, int out_size, void* d_ws, size_t ws_size,
                              hipStream_t stream) {
  const float* x   = (const float*)d_in[0];
  const int*   ei  = (const int*)d_in[1];
  // d_in[2] edge_weight: unused by GATConv (edge_dim unset)
  const float* W1  = (const float*)d_in[3];
  const float* aS1 = (const float*)d_in[4];
  const float* aD1 = (const float*)d_in[5];
  const float* b1  = (const float*)d_in[6];
  const float* W2  = (const float*)d_in[7];
  const float* aS2 = (const float*)d_in[8];
  const float* aD2 = (const float*)d_in[9];
  const float* b2  = (const float*)d_in[10];

  const int N  = in_sizes[0] / 128;
  const int E  = in_sizes[2];
  const int ET = E + N;

  float* ws   = (float*)d_ws;
  float* h1   = ws;                           // N*128 (reused as h2 after layer 1)
  float* out1 = h1   + (size_t)N * 128;       // N*128
  float* as1  = out1 + (size_t)N * 128;       // 4N
  float* ad1  = as1  + (size_t)4 * N;         // 4N
  float* as2  = ad1  + (size_t)4 * N;         // N
  float* ad2  = as2  + (size_t)N;             // N
  int*   cnt    = (int*)(ad2 + (size_t)N);    // N
  int*   lcnt   = cnt    + N;                 // 2 (zeroed with cnt)
  int*   rowptr = lcnt   + 2;                 // N+1
  int*   cursor = rowptr + N + 1;             // N
  int*   rowtmp = cursor + N;                 // N
  int*   bsum   = rowtmp + N;                 // 256
  int*   small_list = bsum + 256;             // N
  int*   big_list   = small_list + N;         // N
  int*   srcs   = big_list + N;               // ET
  float* h2   = h1;                           // alias (h1 dead after agg1)
  float* out  = (float*)d_out;                // N*64

  const int eb  = (ET + 255) / 256;
  const int nb  = (N + 255) / 256;            // scan blocks (nb <= 256 required)
  const int gb  = (N + 63) / 64;              // gemm blocks
  const int sb  = (N + 15) / 16;              // small-agg blocks (worst case)
  const int bb  = (N + 3) / 4;                // big-agg blocks (worst case)

  // ---- CSR build (graph shared by both layers) ----
  hipMemsetAsync(cnt, 0, (size_t)(N + 2) * sizeof(int), stream);
  hist_k<<<eb, 256, 0, stream>>>(ei, E, ET, cnt);
  scan1_k<<<nb, 256, 0, stream>>>(cnt, rowtmp, bsum, N);
  scan2_k<<<1, 256, 0, stream>>>(bsum, nb);
  scan3_k<<<nb, 256, 0, stream>>>(rowtmp, bsum, cnt, rowptr, cursor,
                                  small_list, big_list, lcnt, N, ET);
  scatter_k<<<eb, 256, 0, stream>>>(ei, E, ET, cursor, srcs);

  // ---- layer 1 ----
  gemm1_k<<<gb, 256, 0, stream>>>(x, W1, aS1, aD1, h1, as1, ad1, N);
  agg1_small_k<<<sb, 256, 0, stream>>>(rowptr, srcs, as1, ad1, h1, b1, out1,
                                       small_list, lcnt);
  agg1_big_k<<<bb, 256, 0, stream>>>(rowptr, srcs, as1, ad1, h1, b1, out1,
                                     big_list, lcnt);

  // ---- layer 2 ----
  gemm2_k<<<gb, 256, 0, stream>>>(out1, W2, aS2, aD2, h2, as2, ad2, N);
  agg2_small_k<<<sb, 256, 0, stream>>>(rowptr, srcs, as2, ad2, h2, b2, out,
                                       small_list, lcnt);
  agg2_big_k<<<bb, 256, 0, stream>>>(rowptr, srcs, as2, ad2, h2, b2, out,
                                     big_list, lcnt);
}

// Round 9
// 282.867 us; speedup vs baseline: 2.6018x; 1.2921x over previous
//
#include <hip/hip_runtime.h>
#include <math.h>

// GAT (2 layers) on MI355X — radix-partition CSR + degree-bucketed aggregation.
// CSR build: deterministic 2-pass partition by dst (bucket = 128 nodes).
//   histc: per-(block,bucket) counts via LDS (no global atomics)
//   scan_blk/scan_bkt: exact placement offsets
//   passA: edges -> bucket-contiguous packed pairs (LDS cursors, no atomics)
//   passB: one block per bucket: LDS node-hist + scan -> rowptr + srcs,
//          all writes XCD-local (kills the 55 MB cross-XCD line ping-pong
//          the atomic scatter caused), block-aggregated bucket-list append.
// agg small (deg<=16): node per 16-lane group; big: node per wave.

#define NEG_SLOPE 0.2f
#define NBLKA 256      // partition blocks
#define MAXNB 512      // max buckets (N <= 65536)

__device__ __forceinline__ float leaky(float v) { return v > 0.f ? v : NEG_SLOPE * v; }

// ---------------- CSR build: radix partition by dst ----------------
__global__ __launch_bounds__(256) void histc_k(const int* __restrict__ ei, int E, int ET,
                                               int* __restrict__ blkpref, int NB) {
  __shared__ int lhist[MAXNB];
  int chunk = (ET + NBLKA - 1) / NBLKA;
  int e0 = blockIdx.x * chunk, e1 = min(ET, e0 + chunk);
  for (int b = threadIdx.x; b < NB; b += 256) lhist[b] = 0;
  __syncthreads();
  for (int e = e0 + threadIdx.x; e < e1; e += 256) {
    int d = (e < E) ? ei[E + e] : (e - E);
    atomicAdd(&lhist[d >> 7], 1);
  }
  __syncthreads();
  for (int b = threadIdx.x; b < NB; b += 256)
    blkpref[b * NBLKA + blockIdx.x] = lhist[b];
}

// per-bucket exclusive scan over the 256 block counts; total -> bbase[b]
__global__ __launch_bounds__(256) void scan_blk_k(int* __restrict__ blkpref,
                                                  int* __restrict__ bbase) {
  __shared__ int sm[NBLKA];
  int b = blockIdx.x, t = threadIdx.x;
  int v = blkpref[b * NBLKA + t];
  sm[t] = v;
  __syncthreads();
  #pragma unroll
  for (int off = 1; off < NBLKA; off <<= 1) {
    int x = (t >= off) ? sm[t - off] : 0;
    __syncthreads();
    sm[t] += x;
    __syncthreads();
  }
  blkpref[b * NBLKA + t] = sm[t] - v;   // exclusive within bucket
  if (t == NBLKA - 1) bbase[b] = sm[t]; // bucket total
}

// exclusive scan over bucket totals; also zero lcnt, write rowptr[N]
__global__ __launch_bounds__(512) void scan_bkt_k(int* __restrict__ bbase,
                                                  int* __restrict__ lcnt,
                                                  int* __restrict__ rowptr,
                                                  int NB, int N, int ET) {
  __shared__ int sm[512];
  int t = threadIdx.x;
  int v = (t < NB) ? bbase[t] : 0;
  sm[t] = v;
  __syncthreads();
  #pragma unroll
  for (int off = 1; off < 512; off <<= 1) {
    int x = (t >= off) ? sm[t - off] : 0;
    __syncthreads();
    sm[t] += x;
    __syncthreads();
  }
  int excl = sm[t] - v;
  if (t <= NB) bbase[t] = excl;   // bbase[NB] = ET
  if (t == 0) { lcnt[0] = 0; lcnt[16] = 0; rowptr[N] = ET; }
}

// partition edges into bucket-contiguous packed pairs (no global atomics)
__global__ __launch_bounds__(256) void passA_k(const int* __restrict__ ei, int E, int ET,
                                               const int* __restrict__ bbase,
                                               const int* __restrict__ blkpref,
                                               int* __restrict__ pairs, int NB) {
  __shared__ int lcur[MAXNB];
  int chunk = (ET + NBLKA - 1) / NBLKA;
  int e0 = blockIdx.x * chunk, e1 = min(ET, e0 + chunk);
  for (int b = threadIdx.x; b < NB; b += 256)
    lcur[b] = bbase[b] + blkpref[b * NBLKA + blockIdx.x];
  __syncthreads();
  for (int e = e0 + threadIdx.x; e < e1; e += 256) {
    int s, d;
    if (e < E) { s = ei[e]; d = ei[E + e]; } else { s = d = e - E; }
    int b = d >> 7;
    int pos = atomicAdd(&lcur[b], 1);     // LDS atomic only
    pairs[pos] = ((d & 127) << 17) | s;   // s < 2^17
  }
}

// per-bucket: node hist + scan -> rowptr, final srcs placement, bucket lists
__global__ __launch_bounds__(256) void passB_k(const int* __restrict__ pairs,
                                               const int* __restrict__ bbase,
                                               int* __restrict__ rowptr,
                                               int* __restrict__ srcs,
                                               int* __restrict__ small_list,
                                               int* __restrict__ big_list,
                                               int* __restrict__ lcnt, int N) {
  __shared__ int ncnt[128], spre[128], lcur[128];
  __shared__ int wcS[2], wcB[2], bS, bB;
  int b = blockIdx.x, t = threadIdx.x;
  int nb0 = b << 7;
  int nn = min(128, N - nb0);
  int e0 = bbase[b], e1 = bbase[b + 1];
  if (t < 128) ncnt[t] = 0;
  __syncthreads();
  for (int r = e0 + t; r < e1; r += 256)
    atomicAdd(&ncnt[pairs[r] >> 17], 1);
  __syncthreads();
  if (t < 128) spre[t] = ncnt[t];
  __syncthreads();
  #pragma unroll
  for (int off = 1; off < 128; off <<= 1) {
    int x = (t < 128 && t >= off) ? spre[t - off] : 0;
    __syncthreads();
    if (t < 128) spre[t] += x;
    __syncthreads();
  }
  if (t < nn) {
    int base = e0 + spre[t] - ncnt[t];
    rowptr[nb0 + t] = base;
    lcur[t] = base;
  }
  __syncthreads();
  for (int r = e0 + t; r < e1; r += 256) {
    int p = pairs[r];
    int pos = atomicAdd(&lcur[p >> 17], 1);
    srcs[pos] = p & 0x1FFFF;
  }
  // bucket lists (block-aggregated append, lcnt padded to separate lines)
  int lane = t & 63, wv = t >> 6;
  bool valid = (t < nn);
  int deg = valid ? ncnt[t] : 0;
  bool isS = valid && (deg <= 16);
  bool isB = valid && (deg > 16);
  unsigned long long ms = __ballot(isS);
  unsigned long long mb = __ballot(isB);
  if (lane == 0 && wv < 2) { wcS[wv] = __popcll(ms); wcB[wv] = __popcll(mb); }
  __syncthreads();
  if (t == 0) {
    bS = atomicAdd(&lcnt[0],  wcS[0] + wcS[1]);
    bB = atomicAdd(&lcnt[16], wcB[0] + wcB[1]);
  }
  __syncthreads();
  unsigned long long below = (lane == 0) ? 0ull : (~0ull >> (64 - lane));
  int offS = bS + ((wv == 1) ? wcS[0] : 0);
  int offB = bB + ((wv == 1) ? wcB[0] : 0);
  if (isS) small_list[offS + __popcll(ms & below)] = nb0 + t;
  if (isB) big_list[offB + __popcll(mb & below)]   = nb0 + t;
}

// ---------------- GEMM1 + alpha1 ----------------
__global__ __launch_bounds__(256) void gemm1_k(const float* __restrict__ X,
                                               const float* __restrict__ W,
                                               const float* __restrict__ aw_s,
                                               const float* __restrict__ aw_d,
                                               float* __restrict__ Hout,
                                               float* __restrict__ as,
                                               float* __restrict__ ad, int N) {
  __shared__ float wl[32 * 128];
  __shared__ float xt[32][72];
  int cl = threadIdx.x & 31, rg = threadIdx.x >> 5;
  int c4 = cl * 4;
  int n0 = blockIdx.x * 64;
  float acc[8][4] = {};
  const float4* X4 = (const float4*)X;
  const float4* W4 = (const float4*)W;
  for (int k0 = 0; k0 < 128; k0 += 32) {
    __syncthreads();
    for (int i = threadIdx.x; i < 1024; i += 256)
      ((float4*)wl)[i] = W4[k0 * 32 + i];
    for (int i = threadIdx.x; i < 512; i += 256) {
      int r = i >> 3, kk4 = (i & 7) * 4;
      int n = n0 + r;
      float4 xv = (n < N) ? X4[(size_t)n * 32 + (k0 >> 2) + (i & 7)]
                          : make_float4(0.f, 0.f, 0.f, 0.f);
      xt[kk4 + 0][r] = xv.x; xt[kk4 + 1][r] = xv.y;
      xt[kk4 + 2][r] = xv.z; xt[kk4 + 3][r] = xv.w;
    }
    __syncthreads();
    #pragma unroll 8
    for (int kk = 0; kk < 32; ++kk) {
      float4 w4 = *(const float4*)&wl[kk * 128 + c4];
      float4 xa = *(const float4*)&xt[kk][rg * 8];
      float4 xb = *(const float4*)&xt[kk][rg * 8 + 4];
      float xr[8] = {xa.x, xa.y, xa.z, xa.w, xb.x, xb.y, xb.z, xb.w};
      #pragma unroll
      for (int j = 0; j < 8; ++j) {
        acc[j][0] += xr[j] * w4.x; acc[j][1] += xr[j] * w4.y;
        acc[j][2] += xr[j] * w4.z; acc[j][3] += xr[j] * w4.w;
      }
    }
  }
  float4 aws = *(const float4*)&aw_s[c4];
  float4 awd = *(const float4*)&aw_d[c4];
  #pragma unroll
  for (int j = 0; j < 8; ++j) {
    int n = n0 + rg * 8 + j;
    float ps = acc[j][0] * aws.x + acc[j][1] * aws.y + acc[j][2] * aws.z + acc[j][3] * aws.w;
    float pd = acc[j][0] * awd.x + acc[j][1] * awd.y + acc[j][2] * awd.z + acc[j][3] * awd.w;
    ps += __shfl_xor(ps, 1); ps += __shfl_xor(ps, 2); ps += __shfl_xor(ps, 4);
    pd += __shfl_xor(pd, 1); pd += __shfl_xor(pd, 2); pd += __shfl_xor(pd, 4);
    if (n < N) {
      *(float4*)&Hout[(size_t)n * 128 + c4] =
          make_float4(acc[j][0], acc[j][1], acc[j][2], acc[j][3]);
      if ((cl & 7) == 0) {
        as[n * 4 + (cl >> 3)] = ps;
        ad[n * 4 + (cl >> 3)] = pd;
      }
    }
  }
}

// ---------------- GEMM2 + alpha2 ----------------
__global__ __launch_bounds__(256) void gemm2_k(const float* __restrict__ X,
                                               const float* __restrict__ W,
                                               const float* __restrict__ aw_s,
                                               const float* __restrict__ aw_d,
                                               float* __restrict__ Hout,
                                               float* __restrict__ as,
                                               float* __restrict__ ad, int N) {
  __shared__ float wl[32 * 64];
  __shared__ float xt[32][72];
  int cl = threadIdx.x & 15, rg = threadIdx.x >> 4;
  int c4 = cl * 4;
  int n0 = blockIdx.x * 64;
  float acc[4][4] = {};
  const float4* X4 = (const float4*)X;
  const float4* W4 = (const float4*)W;
  for (int k0 = 0; k0 < 128; k0 += 32) {
    __syncthreads();
    for (int i = threadIdx.x; i < 512; i += 256)
      ((float4*)wl)[i] = W4[k0 * 16 + i];
    for (int i = threadIdx.x; i < 512; i += 256) {
      int r = i >> 3, kk4 = (i & 7) * 4;
      int n = n0 + r;
      float4 xv = (n < N) ? X4[(size_t)n * 32 + (k0 >> 2) + (i & 7)]
                          : make_float4(0.f, 0.f, 0.f, 0.f);
      xt[kk4 + 0][r] = xv.x; xt[kk4 + 1][r] = xv.y;
      xt[kk4 + 2][r] = xv.z; xt[kk4 + 3][r] = xv.w;
    }
    __syncthreads();
    #pragma unroll 8
    for (int kk = 0; kk < 32; ++kk) {
      float4 w4 = *(const float4*)&wl[kk * 64 + c4];
      float4 xa = *(const float4*)&xt[kk][rg * 4];
      float xr[4] = {xa.x, xa.y, xa.z, xa.w};
      #pragma unroll
      for (int j = 0; j < 4; ++j) {
        acc[j][0] += xr[j] * w4.x; acc[j][1] += xr[j] * w4.y;
        acc[j][2] += xr[j] * w4.z; acc[j][3] += xr[j] * w4.w;
      }
    }
  }
  float4 aws = *(const float4*)&aw_s[c4];
  float4 awd = *(const float4*)&aw_d[c4];
  #pragma unroll
  for (int j = 0; j < 4; ++j) {
    int n = n0 + rg * 4 + j;
    float ps = acc[j][0] * aws.x + acc[j][1] * aws.y + acc[j][2] * aws.z + acc[j][3] * aws.w;
    float pd = acc[j][0] * awd.x + acc[j][1] * awd.y + acc[j][2] * awd.z + acc[j][3] * awd.w;
    ps += __shfl_xor(ps, 1); ps += __shfl_xor(ps, 2);
    ps += __shfl_xor(ps, 4); ps += __shfl_xor(ps, 8);
    pd += __shfl_xor(pd, 1); pd += __shfl_xor(pd, 2);
    pd += __shfl_xor(pd, 4); pd += __shfl_xor(pd, 8);
    if (n < N) {
      *(float4*)&Hout[(size_t)n * 64 + c4] =
          make_float4(acc[j][0], acc[j][1], acc[j][2], acc[j][3]);
      if (cl == 0) { as[n] = ps; ad[n] = pd; }
    }
  }
}

// ---------------- layer-1 small aggregation: node per 16-lane group ----------------
__global__ __launch_bounds__(256) void agg1_small_k(const int* __restrict__ rowptr,
                                                    const int* __restrict__ srcs,
                                                    const float* __restrict__ as,
                                                    const float* __restrict__ ad,
                                                    const float* __restrict__ Hm,
                                                    const float* __restrict__ bias,
                                                    float* __restrict__ out,
                                                    const int* __restrict__ small_list,
                                                    const int* __restrict__ lcnt) {
  __shared__ float al_sm[16][17][4];
  __shared__ int   sr_sm[16][16];
  int g  = threadIdx.x >> 4;
  int gl = threadIdx.x & 15;
  int gidx = blockIdx.x * 16 + g;
  if (gidx >= lcnt[0]) return;
  int n = small_list[gidx];
  int r0 = rowptr[n];
  int deg = rowptr[n + 1] - r0;        // 1..16
  float4 adn = *(const float4*)&ad[n * 4];

  float e0 = -INFINITY, e1 = -INFINITY, e2 = -INFINITY, e3 = -INFINITY;
  int s = 0;
  if (gl < deg) {
    s = srcs[r0 + gl];
    float4 av = *(const float4*)&as[s * 4];
    e0 = leaky(av.x + adn.x); e1 = leaky(av.y + adn.y);
    e2 = leaky(av.z + adn.z); e3 = leaky(av.w + adn.w);
  }
  sr_sm[g][gl] = s;
  float m0 = e0, m1 = e1, m2 = e2, m3 = e3;
  #pragma unroll
  for (int off = 8; off > 0; off >>= 1) {
    m0 = fmaxf(m0, __shfl_xor(m0, off, 16)); m1 = fmaxf(m1, __shfl_xor(m1, off, 16));
    m2 = fmaxf(m2, __shfl_xor(m2, off, 16)); m3 = fmaxf(m3, __shfl_xor(m3, off, 16));
  }
  float sc0 = (gl < deg) ? __expf(e0 - m0) : 0.f;
  float sc1 = (gl < deg) ? __expf(e1 - m1) : 0.f;
  float sc2 = (gl < deg) ? __expf(e2 - m2) : 0.f;
  float sc3 = (gl < deg) ? __expf(e3 - m3) : 0.f;
  float s0 = sc0, s1 = sc1, s2 = sc2, s3 = sc3;
  #pragma unroll
  for (int off = 8; off > 0; off >>= 1) {
    s0 += __shfl_xor(s0, off, 16); s1 += __shfl_xor(s1, off, 16);
    s2 += __shfl_xor(s2, off, 16); s3 += __shfl_xor(s3, off, 16);
  }
  *(float4*)&al_sm[g][gl][0] =
      make_float4(sc0 / s0, sc1 / s1, sc2 / s2, sc3 / s3);

  int h = gl >> 2;
  int cbase = gl * 8;
  float a0 = 0.f, a1 = 0.f, a2 = 0.f, a3 = 0.f,
        a4 = 0.f, a5 = 0.f, a6 = 0.f, a7 = 0.f;
  for (int j = 0; j < deg; j += 4) {
    #pragma unroll
    for (int u = 0; u < 4; ++u) {
      int idx = j + u;
      bool vU = idx < deg;
      int jj = vU ? idx : 0;
      int   sU  = sr_sm[g][jj];
      float alU = vU ? al_sm[g][jj][h] : 0.f;
      const float* row = &Hm[(size_t)sU * 128 + cbase];
      float4 h0 = *(const float4*)row;
      float4 h1 = *(const float4*)(row + 4);
      a0 += h0.x * alU; a1 += h0.y * alU; a2 += h0.z * alU; a3 += h0.w * alU;
      a4 += h1.x * alU; a5 += h1.y * alU; a6 += h1.z * alU; a7 += h1.w * alU;
    }
  }
  float4 b0 = *(const float4*)&bias[cbase];
  float4 b1 = *(const float4*)&bias[cbase + 4];
  float4 o0, o1;
  o0.x = fmaxf(a0 + b0.x, 0.f); o0.y = fmaxf(a1 + b0.y, 0.f);
  o0.z = fmaxf(a2 + b0.z, 0.f); o0.w = fmaxf(a3 + b0.w, 0.f);
  o1.x = fmaxf(a4 + b1.x, 0.f); o1.y = fmaxf(a5 + b1.y, 0.f);
  o1.z = fmaxf(a6 + b1.z, 0.f); o1.w = fmaxf(a7 + b1.w, 0.f);
  *(float4*)&out[(size_t)n * 128 + cbase] = o0;
  *(float4*)&out[(size_t)n * 128 + cbase + 4] = o1;
}

// ---------------- layer-1 big aggregation: node per wave ----------------
__global__ __launch_bounds__(256) void agg1_big_k(const int* __restrict__ rowptr,
                                                  const int* __restrict__ srcs,
                                                  const float* __restrict__ as,
                                                  const float* __restrict__ ad,
                                                  const float* __restrict__ Hm,
                                                  const float* __restrict__ bias,
                                                  float* __restrict__ out,
                                                  const int* __restrict__ big_list,
                                                  const int* __restrict__ lcnt) {
  __shared__ float al_sm[4][64][4];
  __shared__ int   sr_sm[4][64];
  int wv = threadIdx.x >> 6, lane = threadIdx.x & 63;
  int widx = blockIdx.x * 4 + wv;
  if (widx >= lcnt[16]) return;
  int n = big_list[widx];
  int r0 = rowptr[n], r1 = rowptr[n + 1];
  int deg = r1 - r0;
  int grp = lane >> 4, gl = lane & 15, h = gl >> 2;
  int cbase = gl * 8;
  float4 adn = *(const float4*)&ad[n * 4];

  float a0 = 0.f, a1 = 0.f, a2 = 0.f, a3 = 0.f,
        a4 = 0.f, a5 = 0.f, a6 = 0.f, a7 = 0.f;

  if (deg <= 64) {
    float e0 = -INFINITY, e1 = -INFINITY, e2 = -INFINITY, e3 = -INFINITY;
    int s = 0;
    if (lane < deg) {
      s = srcs[r0 + lane];
      float4 av = *(const float4*)&as[s * 4];
      e0 = leaky(av.x + adn.x); e1 = leaky(av.y + adn.y);
      e2 = leaky(av.z + adn.z); e3 = leaky(av.w + adn.w);
    }
    sr_sm[wv][lane] = s;
    float m0 = e0, m1 = e1, m2 = e2, m3 = e3;
    #pragma unroll
    for (int off = 32; off > 0; off >>= 1) {
      m0 = fmaxf(m0, __shfl_xor(m0, off)); m1 = fmaxf(m1, __shfl_xor(m1, off));
      m2 = fmaxf(m2, __shfl_xor(m2, off)); m3 = fmaxf(m3, __shfl_xor(m3, off));
    }
    float sc0 = (lane < deg) ? __expf(e0 - m0) : 0.f;
    float sc1 = (lane < deg) ? __expf(e1 - m1) : 0.f;
    float sc2 = (lane < deg) ? __expf(e2 - m2) : 0.f;
    float sc3 = (lane < deg) ? __expf(e3 - m3) : 0.f;
    float s0 = sc0, s1 = sc1, s2 = sc2, s3 = sc3;
    #pragma unroll
    for (int off = 32; off > 0; off >>= 1) {
      s0 += __shfl_xor(s0, off); s1 += __shfl_xor(s1, off);
      s2 += __shfl_xor(s2, off); s3 += __shfl_xor(s3, off);
    }
    *(float4*)&al_sm[wv][lane][0] =
        make_float4(sc0 / s0, sc1 / s1, sc2 / s2, sc3 / s3);

    for (int base = 0; base < deg; base += 16) {
      #pragma unroll
      for (int u = 0; u < 4; ++u) {
        int idx = base + grp * 4 + u;
        bool vU = idx < deg;
        int jj = vU ? idx : 0;
        int   sU  = sr_sm[wv][jj];
        float alU = vU ? al_sm[wv][jj][h] : 0.f;
        const float* row = &Hm[(size_t)sU * 128 + cbase];
        float4 h0 = *(const float4*)row;
        float4 h1 = *(const float4*)(row + 4);
        a0 += h0.x * alU; a1 += h0.y * alU; a2 += h0.z * alU; a3 += h0.w * alU;
        a4 += h1.x * alU; a5 += h1.y * alU; a6 += h1.z * alU; a7 += h1.w * alU;
      }
    }
  } else {
    float m0 = -INFINITY, m1 = -INFINITY, m2 = -INFINITY, m3 = -INFINITY;
    for (int r = r0 + lane; r < r1; r += 64) {
      int s = srcs[r];
      float4 av = *(const float4*)&as[s * 4];
      m0 = fmaxf(m0, leaky(av.x + adn.x)); m1 = fmaxf(m1, leaky(av.y + adn.y));
      m2 = fmaxf(m2, leaky(av.z + adn.z)); m3 = fmaxf(m3, leaky(av.w + adn.w));
    }
    #pragma unroll
    for (int off = 32; off > 0; off >>= 1) {
      m0 = fmaxf(m0, __shfl_xor(m0, off)); m1 = fmaxf(m1, __shfl_xor(m1, off));
      m2 = fmaxf(m2, __shfl_xor(m2, off)); m3 = fmaxf(m3, __shfl_xor(m3, off));
    }
    float s0 = 0.f, s1 = 0.f, s2 = 0.f, s3 = 0.f;
    for (int r = r0 + lane; r < r1; r += 64) {
      int s = srcs[r];
      float4 av = *(const float4*)&as[s * 4];
      s0 += __expf(leaky(av.x + adn.x) - m0); s1 += __expf(leaky(av.y + adn.y) - m1);
      s2 += __expf(leaky(av.z + adn.z) - m2); s3 += __expf(leaky(av.w + adn.w) - m3);
    }
    #pragma unroll
    for (int off = 32; off > 0; off >>= 1) {
      s0 += __shfl_xor(s0, off); s1 += __shfl_xor(s1, off);
      s2 += __shfl_xor(s2, off); s3 += __shfl_xor(s3, off);
    }
    float mhh = (h == 0) ? m0 : (h == 1) ? m1 : (h == 2) ? m2 : m3;
    float inv = 1.f / ((h == 0) ? s0 : (h == 1) ? s1 : (h == 2) ? s2 : s3);
    float adh = (h == 0) ? adn.x : (h == 1) ? adn.y : (h == 2) ? adn.z : adn.w;
    for (int r = r0; r < r1; r += 8) {
      int rA = r + grp, rB = rA + 4;
      bool vA = rA < r1, vB = rB < r1;
      int sA = srcs[vA ? rA : r0];
      int sB = srcs[vB ? rB : r0];
      float avA = as[sA * 4 + h], avB = as[sB * 4 + h];
      float alA = vA ? (__expf(leaky(avA + adh) - mhh) * inv) : 0.f;
      float alB = vB ? (__expf(leaky(avB + adh) - mhh) * inv) : 0.f;
      const float* rowA = &Hm[(size_t)sA * 128 + cbase];
      const float* rowB = &Hm[(size_t)sB * 128 + cbase];
      float4 hA0 = *(const float4*)rowA, hA1 = *(const float4*)(rowA + 4);
      float4 hB0 = *(const float4*)rowB, hB1 = *(const float4*)(rowB + 4);
      a0 += hA0.x * alA + hB0.x * alB; a1 += hA0.y * alA + hB0.y * alB;
      a2 += hA0.z * alA + hB0.z * alB; a3 += hA0.w * alA + hB0.w * alB;
      a4 += hA1.x * alA + hB1.x * alB; a5 += hA1.y * alA + hB1.y * alB;
      a6 += hA1.z * alA + hB1.z * alB; a7 += hA1.w * alA + hB1.w * alB;
    }
  }
  a0 += __shfl_xor(a0, 16); a0 += __shfl_xor(a0, 32);
  a1 += __shfl_xor(a1, 16); a1 += __shfl_xor(a1, 32);
  a2 += __shfl_xor(a2, 16); a2 += __shfl_xor(a2, 32);
  a3 += __shfl_xor(a3, 16); a3 += __shfl_xor(a3, 32);
  a4 += __shfl_xor(a4, 16); a4 += __shfl_xor(a4, 32);
  a5 += __shfl_xor(a5, 16); a5 += __shfl_xor(a5, 32);
  a6 += __shfl_xor(a6, 16); a6 += __shfl_xor(a6, 32);
  a7 += __shfl_xor(a7, 16); a7 += __shfl_xor(a7, 32);
  if (grp == 0) {
    float4 b0 = *(const float4*)&bias[cbase];
    float4 b1 = *(const float4*)&bias[cbase + 4];
    float4 o0, o1;
    o0.x = fmaxf(a0 + b0.x, 0.f); o0.y = fmaxf(a1 + b0.y, 0.f);
    o0.z = fmaxf(a2 + b0.z, 0.f); o0.w = fmaxf(a3 + b0.w, 0.f);
    o1.x = fmaxf(a4 + b1.x, 0.f); o1.y = fmaxf(a5 + b1.y, 0.f);
    o1.z = fmaxf(a6 + b1.z, 0.f); o1.w = fmaxf(a7 + b1.w, 0.f);
    *(float4*)&out[(size_t)n * 128 + cbase] = o0;
    *(float4*)&out[(size_t)n * 128 + cbase + 4] = o1;
  }
}

// ---------------- layer-2 small aggregation (H=1,C=64) ----------------
__global__ __launch_bounds__(256) void agg2_small_k(const int* __restrict__ rowptr,
                                                    const int* __restrict__ srcs,
                                                    const float* __restrict__ as,
                                                    const float* __restrict__ ad,
                                                    const float* __restrict__ Hm,
                                                    const float* __restrict__ bias,
                                                    float* __restrict__ out,
                                                    const int* __restrict__ small_list,
                                                    const int* __restrict__ lcnt) {
  __shared__ float al_sm[16][17];
  __shared__ int   sr_sm[16][16];
  int g  = threadIdx.x >> 4;
  int gl = threadIdx.x & 15;
  int gidx = blockIdx.x * 16 + g;
  if (gidx >= lcnt[0]) return;
  int n = small_list[gidx];
  int r0 = rowptr[n];
  int deg = rowptr[n + 1] - r0;
  float adn = ad[n];

  float e = -INFINITY;
  int s = 0;
  if (gl < deg) { s = srcs[r0 + gl]; e = leaky(as[s] + adn); }
  sr_sm[g][gl] = s;
  float m = e;
  #pragma unroll
  for (int off = 8; off > 0; off >>= 1) m = fmaxf(m, __shfl_xor(m, off, 16));
  float sc = (gl < deg) ? __expf(e - m) : 0.f;
  float ssum = sc;
  #pragma unroll
  for (int off = 8; off > 0; off >>= 1) ssum += __shfl_xor(ssum, off, 16);
  al_sm[g][gl] = sc / ssum;

  int cbase = gl * 4;
  float a0 = 0.f, a1 = 0.f, a2 = 0.f, a3 = 0.f;
  for (int j = 0; j < deg; j += 4) {
    #pragma unroll
    for (int u = 0; u < 4; ++u) {
      int idx = j + u;
      bool vU = idx < deg;
      int jj = vU ? idx : 0;
      int   sU  = sr_sm[g][jj];
      float alU = vU ? al_sm[g][jj] : 0.f;
      float4 hv = *(const float4*)&Hm[(size_t)sU * 64 + cbase];
      a0 += hv.x * alU; a1 += hv.y * alU; a2 += hv.z * alU; a3 += hv.w * alU;
    }
  }
  float4 bv = *(const float4*)&bias[cbase];
  float4 o;
  o.x = a0 + bv.x; o.y = a1 + bv.y; o.z = a2 + bv.z; o.w = a3 + bv.w;
  *(float4*)&out[(size_t)n * 64 + cbase] = o;
}

// ---------------- layer-2 big aggregation: node per wave ----------------
__global__ __launch_bounds__(256) void agg2_big_k(const int* __restrict__ rowptr,
                                                  const int* __restrict__ srcs,
                                                  const float* __restrict__ as,
                                                  const float* __restrict__ ad,
                                                  const float* __restrict__ Hm,
                                                  const float* __restrict__ bias,
                                                  float* __restrict__ out,
                                                  const int* __restrict__ big_list,
                                                  const int* __restrict__ lcnt) {
  __shared__ float al_sm[4][64];
  __shared__ int   sr_sm[4][64];
  int wv = threadIdx.x >> 6, lane = threadIdx.x & 63;
  int widx = blockIdx.x * 4 + wv;
  if (widx >= lcnt[16]) return;
  int n = big_list[widx];
  int r0 = rowptr[n], r1 = rowptr[n + 1];
  int deg = r1 - r0;
  int grp = lane >> 4, gl = lane & 15;
  int cbase = gl * 4;
  float adn = ad[n];

  float a0 = 0.f, a1 = 0.f, a2 = 0.f, a3 = 0.f;

  if (deg <= 64) {
    float e = -INFINITY;
    int s = 0;
    if (lane < deg) { s = srcs[r0 + lane]; e = leaky(as[s] + adn); }
    sr_sm[wv][lane] = s;
    float m = e;
    #pragma unroll
    for (int off = 32; off > 0; off >>= 1) m = fmaxf(m, __shfl_xor(m, off));
    float sc = (lane < deg) ? __expf(e - m) : 0.f;
    float ssum = sc;
    #pragma unroll
    for (int off = 32; off > 0; off >>= 1) ssum += __shfl_xor(ssum, off);
    al_sm[wv][lane] = sc / ssum;

    for (int base = 0; base < deg; base += 16) {
      #pragma unroll
      for (int u = 0; u < 4; ++u) {
        int idx = base + grp * 4 + u;
        bool vU = idx < deg;
        int jj = vU ? idx : 0;
        int   sU  = sr_sm[wv][jj];
        float alU = vU ? al_sm[wv][jj] : 0.f;
        float4 hv = *(const float4*)&Hm[(size_t)sU * 64 + cbase];
        a0 += hv.x * alU; a1 += hv.y * alU; a2 += hv.z * alU; a3 += hv.w * alU;
      }
    }
  } else {
    float mh = -INFINITY;
    for (int r = r0 + lane; r < r1; r += 64)
      mh = fmaxf(mh, leaky(as[srcs[r]] + adn));
    #pragma unroll
    for (int off = 32; off > 0; off >>= 1) mh = fmaxf(mh, __shfl_xor(mh, off));
    float ssum = 0.f;
    for (int r = r0 + lane; r < r1; r += 64)
      ssum += __expf(leaky(as[srcs[r]] + adn) - mh);
    #pragma unroll
    for (int off = 32; off > 0; off >>= 1) ssum += __shfl_xor(ssum, off);
    float inv = 1.f / ssum;
    for (int r = r0; r < r1; r += 8) {
      int rA = r + grp, rB = rA + 4;
      bool vA = rA < r1, vB = rB < r1;
      int sA = srcs[vA ? rA : r0];
      int sB = srcs[vB ? rB : r0];
      float alA = vA ? (__expf(leaky(as[sA] + adn) - mh) * inv) : 0.f;
      float alB = vB ? (__expf(leaky(as[sB] + adn) - mh) * inv) : 0.f;
      float4 hA = *(const float4*)&Hm[(size_t)sA * 64 + cbase];
      float4 hB = *(const float4*)&Hm[(size_t)sB * 64 + cbase];
      a0 += hA.x * alA + hB.x * alB; a1 += hA.y * alA + hB.y * alB;
      a2 += hA.z * alA + hB.z * alB; a3 += hA.w * alA + hB.w * alB;
    }
  }
  a0 += __shfl_xor(a0, 16); a0 += __shfl_xor(a0, 32);
  a1 += __shfl_xor(a1, 16); a1 += __shfl_xor(a1, 32);
  a2 += __shfl_xor(a2, 16); a2 += __shfl_xor(a2, 32);
  a3 += __shfl_xor(a3, 16); a3 += __shfl_xor(a3, 32);
  if (grp == 0) {
    float4 bv = *(const float4*)&bias[cbase];
    float4 o;
    o.x = a0 + bv.x; o.y = a1 + bv.y; o.z = a2 + bv.z; o.w = a3 + bv.w;
    *(float4*)&out[(size_t)n * 64 + cbase] = o;
  }
}

extern "C" void kernel_launch(void* const* d_in, const int* in_sizes, int n_in,
                              void* d_out, int out_size, void* d_ws, size_t ws_size,
                              hipStream_t stream) {
  const float* x   = (const float*)d_in[0];
  const int*   ei  = (const int*)d_in[1];
  // d_in[2] edge_weight: unused by GATConv (edge_dim unset)
  const float* W1  = (const float*)d_in[3];
  const float* aS1 = (const float*)d_in[4];
  const float* aD1 = (const float*)d_in[5];
  const float* b1  = (const float*)d_in[6];
  const float* W2  = (const float*)d_in[7];
  const float* aS2 = (const float*)d_in[8];
  const float* aD2 = (const float*)d_in[9];
  const float* b2  = (const float*)d_in[10];

  const int N  = in_sizes[0] / 128;
  const int E  = in_sizes[2];
  const int ET = E + N;
  const int NB = (N + 127) >> 7;              // 128-node buckets

  float* ws   = (float*)d_ws;
  float* h1   = ws;                           // N*128 (reused as h2; pairs aliased here pre-gemm1)
  float* out1 = h1   + (size_t)N * 128;       // N*128
  float* as1  = out1 + (size_t)N * 128;       // 4N
  float* ad1  = as1  + (size_t)4 * N;         // 4N
  float* as2  = ad1  + (size_t)4 * N;         // N
  float* ad2  = as2  + (size_t)N;             // N
  int*   lcnt    = (int*)(ad2 + (size_t)N);   // 32 (padded: [0]=small,[16]=big)
  int*   rowptr  = lcnt + 32;                 // N+1
  int*   bbase   = rowptr + N + 1;            // NB+1
  int*   blkpref = bbase + NB + 1;            // NB*NBLKA
  int*   small_list = blkpref + NB * NBLKA;   // N
  int*   big_list   = small_list + N;         // N
  int*   srcs   = big_list + N;               // ET
  int*   pairs  = (int*)h1;                   // ET (aliased; dead before gemm1)
  float* h2   = h1;
  float* out  = (float*)d_out;                // N*64

  const int gb  = (N + 63) / 64;              // gemm blocks
  const int sb  = (N + 15) / 16;              // small-agg blocks (worst case)
  const int bb  = (N + 3) / 4;                // big-agg blocks (worst case)

  // ---- CSR build: deterministic radix partition ----
  histc_k<<<NBLKA, 256, 0, stream>>>(ei, E, ET, blkpref, NB);
  scan_blk_k<<<NB, 256, 0, stream>>>(blkpref, bbase);
  scan_bkt_k<<<1, 512, 0, stream>>>(bbase, lcnt, rowptr, NB, N, ET);
  passA_k<<<NBLKA, 256, 0, stream>>>(ei, E, ET, bbase, blkpref, pairs, NB);
  passB_k<<<NB, 256, 0, stream>>>(pairs, bbase, rowptr, srcs,
                                  small_list, big_list, lcnt, N);

  // ---- layer 1 ----
  gemm1_k<<<gb, 256, 0, stream>>>(x, W1, aS1, aD1, h1, as1, ad1, N);
  agg1_small_k<<<sb, 256, 0, stream>>>(rowptr, srcs, as1, ad1, h1, b1, out1,
                                       small_list, lcnt);
  agg1_big_k<<<bb, 256, 0, stream>>>(rowptr, srcs, as1, ad1, h1, b1, out1,
                                     big_list, lcnt);

  // ---- layer 2 ----
  gemm2_k<<<gb, 256, 0, stream>>>(out1, W2, aS2, aD2, h2, as2, ad2, N);
  agg2_small_k<<<sb, 256, 0, stream>>>(rowptr, srcs, as2, ad2, h2, b2, out,
                                       small_list, lcnt);
  agg2_big_k<<<bb, 256, 0, stream>>>(rowptr, srcs, as2, ad2, h2, b2, out,
                                     big_list, lcnt);
}

// Round 10
// 243.916 us; speedup vs baseline: 3.0173x; 1.1597x over previous
//
#include <hip/hip_runtime.h>
#include <hip/hip_fp16.h>
#include <math.h>

// GAT (2 layers) on MI355X — radix-partition CSR + degree-bucketed aggregation,
// fp16 h-gather (h stored fp16: agg gather traffic halves; as/ad/accum fp32).
// CSR build: deterministic 2-pass partition by dst (bucket = 128 nodes), no
// global atomics in the edge passes (cross-XCD line ping-pong costs 55 MB).
// agg small (deg<=16): node per 16-lane group; big: node per wave.

#define NEG_SLOPE 0.2f
#define NBLKA 256      // partition blocks
#define MAXNB 512      // max buckets (N <= 65536)

__device__ __forceinline__ float leaky(float v) { return v > 0.f ? v : NEG_SLOPE * v; }

// ---------------- CSR build: radix partition by dst ----------------
__global__ __launch_bounds__(256) void histc_k(const int* __restrict__ ei, int E, int ET,
                                               int* __restrict__ blkpref, int NB) {
  __shared__ int lhist[MAXNB];
  int chunk = (ET + NBLKA - 1) / NBLKA;
  int e0 = blockIdx.x * chunk, e1 = min(ET, e0 + chunk);
  for (int b = threadIdx.x; b < NB; b += 256) lhist[b] = 0;
  __syncthreads();
  for (int e = e0 + threadIdx.x; e < e1; e += 256) {
    int d = (e < E) ? ei[E + e] : (e - E);
    atomicAdd(&lhist[d >> 7], 1);
  }
  __syncthreads();
  for (int b = threadIdx.x; b < NB; b += 256)
    blkpref[b * NBLKA + blockIdx.x] = lhist[b];
}

__global__ __launch_bounds__(256) void scan_blk_k(int* __restrict__ blkpref,
                                                  int* __restrict__ bbase) {
  __shared__ int sm[NBLKA];
  int b = blockIdx.x, t = threadIdx.x;
  int v = blkpref[b * NBLKA + t];
  sm[t] = v;
  __syncthreads();
  #pragma unroll
  for (int off = 1; off < NBLKA; off <<= 1) {
    int x = (t >= off) ? sm[t - off] : 0;
    __syncthreads();
    sm[t] += x;
    __syncthreads();
  }
  blkpref[b * NBLKA + t] = sm[t] - v;
  if (t == NBLKA - 1) bbase[b] = sm[t];
}

__global__ __launch_bounds__(512) void scan_bkt_k(int* __restrict__ bbase,
                                                  int* __restrict__ lcnt,
                                                  int* __restrict__ rowptr,
                                                  int NB, int N, int ET) {
  __shared__ int sm[512];
  int t = threadIdx.x;
  int v = (t < NB) ? bbase[t] : 0;
  sm[t] = v;
  __syncthreads();
  #pragma unroll
  for (int off = 1; off < 512; off <<= 1) {
    int x = (t >= off) ? sm[t - off] : 0;
    __syncthreads();
    sm[t] += x;
    __syncthreads();
  }
  int excl = sm[t] - v;
  if (t <= NB) bbase[t] = excl;
  if (t == 0) { lcnt[0] = 0; lcnt[16] = 0; rowptr[N] = ET; }
}

__global__ __launch_bounds__(256) void passA_k(const int* __restrict__ ei, int E, int ET,
                                               const int* __restrict__ bbase,
                                               const int* __restrict__ blkpref,
                                               int* __restrict__ pairs, int NB) {
  __shared__ int lcur[MAXNB];
  int chunk = (ET + NBLKA - 1) / NBLKA;
  int e0 = blockIdx.x * chunk, e1 = min(ET, e0 + chunk);
  for (int b = threadIdx.x; b < NB; b += 256)
    lcur[b] = bbase[b] + blkpref[b * NBLKA + blockIdx.x];
  __syncthreads();
  for (int e = e0 + threadIdx.x; e < e1; e += 256) {
    int s, d;
    if (e < E) { s = ei[e]; d = ei[E + e]; } else { s = d = e - E; }
    int b = d >> 7;
    int pos = atomicAdd(&lcur[b], 1);
    pairs[pos] = ((d & 127) << 17) | s;
  }
}

__global__ __launch_bounds__(256) void passB_k(const int* __restrict__ pairs,
                                               const int* __restrict__ bbase,
                                               int* __restrict__ rowptr,
                                               int* __restrict__ srcs,
                                               int* __restrict__ small_list,
                                               int* __restrict__ big_list,
                                               int* __restrict__ lcnt, int N) {
  __shared__ int ncnt[128], spre[128], lcur[128];
  __shared__ int wcS[2], wcB[2], bS, bB;
  int b = blockIdx.x, t = threadIdx.x;
  int nb0 = b << 7;
  int nn = min(128, N - nb0);
  int e0 = bbase[b], e1 = bbase[b + 1];
  if (t < 128) ncnt[t] = 0;
  __syncthreads();
  for (int r = e0 + t; r < e1; r += 256)
    atomicAdd(&ncnt[pairs[r] >> 17], 1);
  __syncthreads();
  if (t < 128) spre[t] = ncnt[t];
  __syncthreads();
  #pragma unroll
  for (int off = 1; off < 128; off <<= 1) {
    int x = (t < 128 && t >= off) ? spre[t - off] : 0;
    __syncthreads();
    if (t < 128) spre[t] += x;
    __syncthreads();
  }
  if (t < nn) {
    int base = e0 + spre[t] - ncnt[t];
    rowptr[nb0 + t] = base;
    lcur[t] = base;
  }
  __syncthreads();
  for (int r = e0 + t; r < e1; r += 256) {
    int p = pairs[r];
    int pos = atomicAdd(&lcur[p >> 17], 1);
    srcs[pos] = p & 0x1FFFF;
  }
  int lane = t & 63, wv = t >> 6;
  bool valid = (t < nn);
  int deg = valid ? ncnt[t] : 0;
  bool isS = valid && (deg <= 16);
  bool isB = valid && (deg > 16);
  unsigned long long ms = __ballot(isS);
  unsigned long long mb = __ballot(isB);
  if (lane == 0 && wv < 2) { wcS[wv] = __popcll(ms); wcB[wv] = __popcll(mb); }
  __syncthreads();
  if (t == 0) {
    bS = atomicAdd(&lcnt[0],  wcS[0] + wcS[1]);
    bB = atomicAdd(&lcnt[16], wcB[0] + wcB[1]);
  }
  __syncthreads();
  unsigned long long below = (lane == 0) ? 0ull : (~0ull >> (64 - lane));
  int offS = bS + ((wv == 1) ? wcS[0] : 0);
  int offB = bB + ((wv == 1) ? wcB[0] : 0);
  if (isS) small_list[offS + __popcll(ms & below)] = nb0 + t;
  if (isB) big_list[offB + __popcll(mb & below)]   = nb0 + t;
}

// ---------------- GEMM1 + alpha1: h1h (fp16) = X @ W1; as/ad fp32 ----------------
__global__ __launch_bounds__(256) void gemm1_k(const float* __restrict__ X,
                                               const float* __restrict__ W,
                                               const float* __restrict__ aw_s,
                                               const float* __restrict__ aw_d,
                                               __half* __restrict__ Hh,
                                               float* __restrict__ as,
                                               float* __restrict__ ad, int N) {
  __shared__ float wl[32 * 128];
  __shared__ float xt[32][72];
  int cl = threadIdx.x & 31, rg = threadIdx.x >> 5;
  int c4 = cl * 4;
  int n0 = blockIdx.x * 64;
  float acc[8][4] = {};
  const float4* X4 = (const float4*)X;
  const float4* W4 = (const float4*)W;
  for (int k0 = 0; k0 < 128; k0 += 32) {
    __syncthreads();
    for (int i = threadIdx.x; i < 1024; i += 256)
      ((float4*)wl)[i] = W4[k0 * 32 + i];
    for (int i = threadIdx.x; i < 512; i += 256) {
      int r = i >> 3, kk4 = (i & 7) * 4;
      int n = n0 + r;
      float4 xv = (n < N) ? X4[(size_t)n * 32 + (k0 >> 2) + (i & 7)]
                          : make_float4(0.f, 0.f, 0.f, 0.f);
      xt[kk4 + 0][r] = xv.x; xt[kk4 + 1][r] = xv.y;
      xt[kk4 + 2][r] = xv.z; xt[kk4 + 3][r] = xv.w;
    }
    __syncthreads();
    #pragma unroll 8
    for (int kk = 0; kk < 32; ++kk) {
      float4 w4 = *(const float4*)&wl[kk * 128 + c4];
      float4 xa = *(const float4*)&xt[kk][rg * 8];
      float4 xb = *(const float4*)&xt[kk][rg * 8 + 4];
      float xr[8] = {xa.x, xa.y, xa.z, xa.w, xb.x, xb.y, xb.z, xb.w};
      #pragma unroll
      for (int j = 0; j < 8; ++j) {
        acc[j][0] += xr[j] * w4.x; acc[j][1] += xr[j] * w4.y;
        acc[j][2] += xr[j] * w4.z; acc[j][3] += xr[j] * w4.w;
      }
    }
  }
  float4 aws = *(const float4*)&aw_s[c4];
  float4 awd = *(const float4*)&aw_d[c4];
  #pragma unroll
  for (int j = 0; j < 8; ++j) {
    int n = n0 + rg * 8 + j;
    float ps = acc[j][0] * aws.x + acc[j][1] * aws.y + acc[j][2] * aws.z + acc[j][3] * aws.w;
    float pd = acc[j][0] * awd.x + acc[j][1] * awd.y + acc[j][2] * awd.z + acc[j][3] * awd.w;
    ps += __shfl_xor(ps, 1); ps += __shfl_xor(ps, 2); ps += __shfl_xor(ps, 4);
    pd += __shfl_xor(pd, 1); pd += __shfl_xor(pd, 2); pd += __shfl_xor(pd, 4);
    if (n < N) {
      __half2 p0 = __floats2half2_rn(acc[j][0], acc[j][1]);
      __half2 p1 = __floats2half2_rn(acc[j][2], acc[j][3]);
      __half2* dst = (__half2*)&Hh[(size_t)n * 128 + c4];
      dst[0] = p0; dst[1] = p1;
      if ((cl & 7) == 0) {
        as[n * 4 + (cl >> 3)] = ps;
        ad[n * 4 + (cl >> 3)] = pd;
      }
    }
  }
}

// ---------------- GEMM2 + alpha2: h2h (fp16) = X @ W2; as2/ad2 fp32 ----------------
__global__ __launch_bounds__(256) void gemm2_k(const float* __restrict__ X,
                                               const float* __restrict__ W,
                                               const float* __restrict__ aw_s,
                                               const float* __restrict__ aw_d,
                                               __half* __restrict__ Hh,
                                               float* __restrict__ as,
                                               float* __restrict__ ad, int N) {
  __shared__ float wl[32 * 64];
  __shared__ float xt[32][72];
  int cl = threadIdx.x & 15, rg = threadIdx.x >> 4;
  int c4 = cl * 4;
  int n0 = blockIdx.x * 64;
  float acc[4][4] = {};
  const float4* X4 = (const float4*)X;
  const float4* W4 = (const float4*)W;
  for (int k0 = 0; k0 < 128; k0 += 32) {
    __syncthreads();
    for (int i = threadIdx.x; i < 512; i += 256)
      ((float4*)wl)[i] = W4[k0 * 16 + i];
    for (int i = threadIdx.x; i < 512; i += 256) {
      int r = i >> 3, kk4 = (i & 7) * 4;
      int n = n0 + r;
      float4 xv = (n < N) ? X4[(size_t)n * 32 + (k0 >> 2) + (i & 7)]
                          : make_float4(0.f, 0.f, 0.f, 0.f);
      xt[kk4 + 0][r] = xv.x; xt[kk4 + 1][r] = xv.y;
      xt[kk4 + 2][r] = xv.z; xt[kk4 + 3][r] = xv.w;
    }
    __syncthreads();
    #pragma unroll 8
    for (int kk = 0; kk < 32; ++kk) {
      float4 w4 = *(const float4*)&wl[kk * 64 + c4];
      float4 xa = *(const float4*)&xt[kk][rg * 4];
      float xr[4] = {xa.x, xa.y, xa.z, xa.w};
      #pragma unroll
      for (int j = 0; j < 4; ++j) {
        acc[j][0] += xr[j] * w4.x; acc[j][1] += xr[j] * w4.y;
        acc[j][2] += xr[j] * w4.z; acc[j][3] += xr[j] * w4.w;
      }
    }
  }
  float4 aws = *(const float4*)&aw_s[c4];
  float4 awd = *(const float4*)&aw_d[c4];
  #pragma unroll
  for (int j = 0; j < 4; ++j) {
    int n = n0 + rg * 4 + j;
    float ps = acc[j][0] * aws.x + acc[j][1] * aws.y + acc[j][2] * aws.z + acc[j][3] * aws.w;
    float pd = acc[j][0] * awd.x + acc[j][1] * awd.y + acc[j][2] * awd.z + acc[j][3] * awd.w;
    ps += __shfl_xor(ps, 1); ps += __shfl_xor(ps, 2);
    ps += __shfl_xor(ps, 4); ps += __shfl_xor(ps, 8);
    pd += __shfl_xor(pd, 1); pd += __shfl_xor(pd, 2);
    pd += __shfl_xor(pd, 4); pd += __shfl_xor(pd, 8);
    if (n < N) {
      __half2 p0 = __floats2half2_rn(acc[j][0], acc[j][1]);
      __half2 p1 = __floats2half2_rn(acc[j][2], acc[j][3]);
      __half2* dst = (__half2*)&Hh[(size_t)n * 64 + c4];
      dst[0] = p0; dst[1] = p1;
      if (cl == 0) { as[n] = ps; ad[n] = pd; }
    }
  }
}

// fp16 row segment (8 halfs) -> 8 floats
__device__ __forceinline__ void load8h(const __half* p, float* f) {
  uint4 hv = *(const uint4*)p;
  float2 f0 = __half22float2(*(const __half2*)&hv.x);
  float2 f1 = __half22float2(*(const __half2*)&hv.y);
  float2 f2 = __half22float2(*(const __half2*)&hv.z);
  float2 f3 = __half22float2(*(const __half2*)&hv.w);
  f[0] = f0.x; f[1] = f0.y; f[2] = f1.x; f[3] = f1.y;
  f[4] = f2.x; f[5] = f2.y; f[6] = f3.x; f[7] = f3.y;
}

// ---------------- layer-1 small aggregation: node per 16-lane group ----------------
__global__ __launch_bounds__(256) void agg1_small_k(const int* __restrict__ rowptr,
                                                    const int* __restrict__ srcs,
                                                    const float* __restrict__ as,
                                                    const float* __restrict__ ad,
                                                    const __half* __restrict__ Hm,
                                                    const float* __restrict__ bias,
                                                    float* __restrict__ out,
                                                    const int* __restrict__ small_list,
                                                    const int* __restrict__ lcnt) {
  __shared__ float al_sm[16][17][4];
  __shared__ int   sr_sm[16][16];
  int g  = threadIdx.x >> 4;
  int gl = threadIdx.x & 15;
  int gidx = blockIdx.x * 16 + g;
  if (gidx >= lcnt[0]) return;
  int n = small_list[gidx];
  int r0 = rowptr[n];
  int deg = rowptr[n + 1] - r0;        // 1..16
  float4 adn = *(const float4*)&ad[n * 4];

  float e0 = -INFINITY, e1 = -INFINITY, e2 = -INFINITY, e3 = -INFINITY;
  int s = 0;
  if (gl < deg) {
    s = srcs[r0 + gl];
    float4 av = *(const float4*)&as[s * 4];
    e0 = leaky(av.x + adn.x); e1 = leaky(av.y + adn.y);
    e2 = leaky(av.z + adn.z); e3 = leaky(av.w + adn.w);
  }
  sr_sm[g][gl] = s;
  float m0 = e0, m1 = e1, m2 = e2, m3 = e3;
  #pragma unroll
  for (int off = 8; off > 0; off >>= 1) {
    m0 = fmaxf(m0, __shfl_xor(m0, off, 16)); m1 = fmaxf(m1, __shfl_xor(m1, off, 16));
    m2 = fmaxf(m2, __shfl_xor(m2, off, 16)); m3 = fmaxf(m3, __shfl_xor(m3, off, 16));
  }
  float sc0 = (gl < deg) ? __expf(e0 - m0) : 0.f;
  float sc1 = (gl < deg) ? __expf(e1 - m1) : 0.f;
  float sc2 = (gl < deg) ? __expf(e2 - m2) : 0.f;
  float sc3 = (gl < deg) ? __expf(e3 - m3) : 0.f;
  float s0 = sc0, s1 = sc1, s2 = sc2, s3 = sc3;
  #pragma unroll
  for (int off = 8; off > 0; off >>= 1) {
    s0 += __shfl_xor(s0, off, 16); s1 += __shfl_xor(s1, off, 16);
    s2 += __shfl_xor(s2, off, 16); s3 += __shfl_xor(s3, off, 16);
  }
  *(float4*)&al_sm[g][gl][0] =
      make_float4(sc0 / s0, sc1 / s1, sc2 / s2, sc3 / s3);

  int h = gl >> 2;
  int cbase = gl * 8;
  float a0 = 0.f, a1 = 0.f, a2 = 0.f, a3 = 0.f,
        a4 = 0.f, a5 = 0.f, a6 = 0.f, a7 = 0.f;
  for (int j = 0; j < deg; j += 4) {
    #pragma unroll
    for (int u = 0; u < 4; ++u) {
      int idx = j + u;
      bool vU = idx < deg;
      int jj = vU ? idx : 0;
      int   sU  = sr_sm[g][jj];
      float alU = vU ? al_sm[g][jj][h] : 0.f;
      float f[8];
      load8h(&Hm[(size_t)sU * 128 + cbase], f);
      a0 += f[0] * alU; a1 += f[1] * alU; a2 += f[2] * alU; a3 += f[3] * alU;
      a4 += f[4] * alU; a5 += f[5] * alU; a6 += f[6] * alU; a7 += f[7] * alU;
    }
  }
  float4 b0 = *(const float4*)&bias[cbase];
  float4 b1 = *(const float4*)&bias[cbase + 4];
  float4 o0, o1;
  o0.x = fmaxf(a0 + b0.x, 0.f); o0.y = fmaxf(a1 + b0.y, 0.f);
  o0.z = fmaxf(a2 + b0.z, 0.f); o0.w = fmaxf(a3 + b0.w, 0.f);
  o1.x = fmaxf(a4 + b1.x, 0.f); o1.y = fmaxf(a5 + b1.y, 0.f);
  o1.z = fmaxf(a6 + b1.z, 0.f); o1.w = fmaxf(a7 + b1.w, 0.f);
  *(float4*)&out[(size_t)n * 128 + cbase] = o0;
  *(float4*)&out[(size_t)n * 128 + cbase + 4] = o1;
}

// ---------------- layer-1 big aggregation: node per wave ----------------
__global__ __launch_bounds__(256) void agg1_big_k(const int* __restrict__ rowptr,
                                                  const int* __restrict__ srcs,
                                                  const float* __restrict__ as,
                                                  const float* __restrict__ ad,
                                                  const __half* __restrict__ Hm,
                                                  const float* __restrict__ bias,
                                                  float* __restrict__ out,
                                                  const int* __restrict__ big_list,
                                                  const int* __restrict__ lcnt) {
  __shared__ float al_sm[4][64][4];
  __shared__ int   sr_sm[4][64];
  int wv = threadIdx.x >> 6, lane = threadIdx.x & 63;
  int widx = blockIdx.x * 4 + wv;
  if (widx >= lcnt[16]) return;
  int n = big_list[widx];
  int r0 = rowptr[n], r1 = rowptr[n + 1];
  int deg = r1 - r0;
  int grp = lane >> 4, gl = lane & 15, h = gl >> 2;
  int cbase = gl * 8;
  float4 adn = *(const float4*)&ad[n * 4];

  float a0 = 0.f, a1 = 0.f, a2 = 0.f, a3 = 0.f,
        a4 = 0.f, a5 = 0.f, a6 = 0.f, a7 = 0.f;

  if (deg <= 64) {
    float e0 = -INFINITY, e1 = -INFINITY, e2 = -INFINITY, e3 = -INFINITY;
    int s = 0;
    if (lane < deg) {
      s = srcs[r0 + lane];
      float4 av = *(const float4*)&as[s * 4];
      e0 = leaky(av.x + adn.x); e1 = leaky(av.y + adn.y);
      e2 = leaky(av.z + adn.z); e3 = leaky(av.w + adn.w);
    }
    sr_sm[wv][lane] = s;
    float m0 = e0, m1 = e1, m2 = e2, m3 = e3;
    #pragma unroll
    for (int off = 32; off > 0; off >>= 1) {
      m0 = fmaxf(m0, __shfl_xor(m0, off)); m1 = fmaxf(m1, __shfl_xor(m1, off));
      m2 = fmaxf(m2, __shfl_xor(m2, off)); m3 = fmaxf(m3, __shfl_xor(m3, off));
    }
    float sc0 = (lane < deg) ? __expf(e0 - m0) : 0.f;
    float sc1 = (lane < deg) ? __expf(e1 - m1) : 0.f;
    float sc2 = (lane < deg) ? __expf(e2 - m2) : 0.f;
    float sc3 = (lane < deg) ? __expf(e3 - m3) : 0.f;
    float s0 = sc0, s1 = sc1, s2 = sc2, s3 = sc3;
    #pragma unroll
    for (int off = 32; off > 0; off >>= 1) {
      s0 += __shfl_xor(s0, off); s1 += __shfl_xor(s1, off);
      s2 += __shfl_xor(s2, off); s3 += __shfl_xor(s3, off);
    }
    *(float4*)&al_sm[wv][lane][0] =
        make_float4(sc0 / s0, sc1 / s1, sc2 / s2, sc3 / s3);

    for (int base = 0; base < deg; base += 16) {
      #pragma unroll
      for (int u = 0; u < 4; ++u) {
        int idx = base + grp * 4 + u;
        bool vU = idx < deg;
        int jj = vU ? idx : 0;
        int   sU  = sr_sm[wv][jj];
        float alU = vU ? al_sm[wv][jj][h] : 0.f;
        float f[8];
        load8h(&Hm[(size_t)sU * 128 + cbase], f);
        a0 += f[0] * alU; a1 += f[1] * alU; a2 += f[2] * alU; a3 += f[3] * alU;
        a4 += f[4] * alU; a5 += f[5] * alU; a6 += f[6] * alU; a7 += f[7] * alU;
      }
    }
  } else {
    float m0 = -INFINITY, m1 = -INFINITY, m2 = -INFINITY, m3 = -INFINITY;
    for (int r = r0 + lane; r < r1; r += 64) {
      int s = srcs[r];
      float4 av = *(const float4*)&as[s * 4];
      m0 = fmaxf(m0, leaky(av.x + adn.x)); m1 = fmaxf(m1, leaky(av.y + adn.y));
      m2 = fmaxf(m2, leaky(av.z + adn.z)); m3 = fmaxf(m3, leaky(av.w + adn.w));
    }
    #pragma unroll
    for (int off = 32; off > 0; off >>= 1) {
      m0 = fmaxf(m0, __shfl_xor(m0, off)); m1 = fmaxf(m1, __shfl_xor(m1, off));
      m2 = fmaxf(m2, __shfl_xor(m2, off)); m3 = fmaxf(m3, __shfl_xor(m3, off));
    }
    float s0 = 0.f, s1 = 0.f, s2 = 0.f, s3 = 0.f;
    for (int r = r0 + lane; r < r1; r += 64) {
      int s = srcs[r];
      float4 av = *(const float4*)&as[s * 4];
      s0 += __expf(leaky(av.x + adn.x) - m0); s1 += __expf(leaky(av.y + adn.y) - m1);
      s2 += __expf(leaky(av.z + adn.z) - m2); s3 += __expf(leaky(av.w + adn.w) - m3);
    }
    #pragma unroll
    for (int off = 32; off > 0; off >>= 1) {
      s0 += __shfl_xor(s0, off); s1 += __shfl_xor(s1, off);
      s2 += __shfl_xor(s2, off); s3 += __shfl_xor(s3, off);
    }
    float mhh = (h == 0) ? m0 : (h == 1) ? m1 : (h == 2) ? m2 : m3;
    float inv = 1.f / ((h == 0) ? s0 : (h == 1) ? s1 : (h == 2) ? s2 : s3);
    float adh = (h == 0) ? adn.x : (h == 1) ? adn.y : (h == 2) ? adn.z : adn.w;
    for (int r = r0; r < r1; r += 8) {
      int rA = r + grp, rB = rA + 4;
      bool vA = rA < r1, vB = rB < r1;
      int sA = srcs[vA ? rA : r0];
      int sB = srcs[vB ? rB : r0];
      float avA = as[sA * 4 + h], avB = as[sB * 4 + h];
      float alA = vA ? (__expf(leaky(avA + adh) - mhh) * inv) : 0.f;
      float alB = vB ? (__expf(leaky(avB + adh) - mhh) * inv) : 0.f;
      float fA[8], fB[8];
      load8h(&Hm[(size_t)sA * 128 + cbase], fA);
      load8h(&Hm[(size_t)sB * 128 + cbase], fB);
      a0 += fA[0] * alA + fB[0] * alB; a1 += fA[1] * alA + fB[1] * alB;
      a2 += fA[2] * alA + fB[2] * alB; a3 += fA[3] * alA + fB[3] * alB;
      a4 += fA[4] * alA + fB[4] * alB; a5 += fA[5] * alA + fB[5] * alB;
      a6 += fA[6] * alA + fB[6] * alB; a7 += fA[7] * alA + fB[7] * alB;
    }
  }
  a0 += __shfl_xor(a0, 16); a0 += __shfl_xor(a0, 32);
  a1 += __shfl_xor(a1, 16); a1 += __shfl_xor(a1, 32);
  a2 += __shfl_xor(a2, 16); a2 += __shfl_xor(a2, 32);
  a3 += __shfl_xor(a3, 16); a3 += __shfl_xor(a3, 32);
  a4 += __shfl_xor(a4, 16); a4 += __shfl_xor(a4, 32);
  a5 += __shfl_xor(a5, 16); a5 += __shfl_xor(a5, 32);
  a6 += __shfl_xor(a6, 16); a6 += __shfl_xor(a6, 32);
  a7 += __shfl_xor(a7, 16); a7 += __shfl_xor(a7, 32);
  if (grp == 0) {
    float4 b0 = *(const float4*)&bias[cbase];
    float4 b1 = *(const float4*)&bias[cbase + 4];
    float4 o0, o1;
    o0.x = fmaxf(a0 + b0.x, 0.f); o0.y = fmaxf(a1 + b0.y, 0.f);
    o0.z = fmaxf(a2 + b0.z, 0.f); o0.w = fmaxf(a3 + b0.w, 0.f);
    o1.x = fmaxf(a4 + b1.x, 0.f); o1.y = fmaxf(a5 + b1.y, 0.f);
    o1.z = fmaxf(a6 + b1.z, 0.f); o1.w = fmaxf(a7 + b1.w, 0.f);
    *(float4*)&out[(size_t)n * 128 + cbase] = o0;
    *(float4*)&out[(size_t)n * 128 + cbase + 4] = o1;
  }
}

// ---------------- layer-2 small aggregation (H=1,C=64) ----------------
__global__ __launch_bounds__(256) void agg2_small_k(const int* __restrict__ rowptr,
                                                    const int* __restrict__ srcs,
                                                    const float* __restrict__ as,
                                                    const float* __restrict__ ad,
                                                    const __half* __restrict__ Hm,
                                                    const float* __restrict__ bias,
                                                    float* __restrict__ out,
                                                    const int* __restrict__ small_list,
                                                    const int* __restrict__ lcnt) {
  __shared__ float al_sm[16][17];
  __shared__ int   sr_sm[16][16];
  int g  = threadIdx.x >> 4;
  int gl = threadIdx.x & 15;
  int gidx = blockIdx.x * 16 + g;
  if (gidx >= lcnt[0]) return;
  int n = small_list[gidx];
  int r0 = rowptr[n];
  int deg = rowptr[n + 1] - r0;
  float adn = ad[n];

  float e = -INFINITY;
  int s = 0;
  if (gl < deg) { s = srcs[r0 + gl]; e = leaky(as[s] + adn); }
  sr_sm[g][gl] = s;
  float m = e;
  #pragma unroll
  for (int off = 8; off > 0; off >>= 1) m = fmaxf(m, __shfl_xor(m, off, 16));
  float sc = (gl < deg) ? __expf(e - m) : 0.f;
  float ssum = sc;
  #pragma unroll
  for (int off = 8; off > 0; off >>= 1) ssum += __shfl_xor(ssum, off, 16);
  al_sm[g][gl] = sc / ssum;

  int cbase = gl * 4;
  float a0 = 0.f, a1 = 0.f, a2 = 0.f, a3 = 0.f;
  for (int j = 0; j < deg; j += 4) {
    #pragma unroll
    for (int u = 0; u < 4; ++u) {
      int idx = j + u;
      bool vU = idx < deg;
      int jj = vU ? idx : 0;
      int   sU  = sr_sm[g][jj];
      float alU = vU ? al_sm[g][jj] : 0.f;
      uint2 hv = *(const uint2*)&Hm[(size_t)sU * 64 + cbase];
      float2 f0 = __half22float2(*(const __half2*)&hv.x);
      float2 f1 = __half22float2(*(const __half2*)&hv.y);
      a0 += f0.x * alU; a1 += f0.y * alU; a2 += f1.x * alU; a3 += f1.y * alU;
    }
  }
  float4 bv = *(const float4*)&bias[cbase];
  float4 o;
  o.x = a0 + bv.x; o.y = a1 + bv.y; o.z = a2 + bv.z; o.w = a3 + bv.w;
  *(float4*)&out[(size_t)n * 64 + cbase] = o;
}

// ---------------- layer-2 big aggregation: node per wave ----------------
__global__ __launch_bounds__(256) void agg2_big_k(const int* __restrict__ rowptr,
                                                  const int* __restrict__ srcs,
                                                  const float* __restrict__ as,
                                                  const float* __restrict__ ad,
                                                  const __half* __restrict__ Hm,
                                                  const float* __restrict__ bias,
                                                  float* __restrict__ out,
                                                  const int* __restrict__ big_list,
                                                  const int* __restrict__ lcnt) {
  __shared__ float al_sm[4][64];
  __shared__ int   sr_sm[4][64];
  int wv = threadIdx.x >> 6, lane = threadIdx.x & 63;
  int widx = blockIdx.x * 4 + wv;
  if (widx >= lcnt[16]) return;
  int n = big_list[widx];
  int r0 = rowptr[n], r1 = rowptr[n + 1];
  int deg = r1 - r0;
  int grp = lane >> 4, gl = lane & 15;
  int cbase = gl * 4;
  float adn = ad[n];

  float a0 = 0.f, a1 = 0.f, a2 = 0.f, a3 = 0.f;

  if (deg <= 64) {
    float e = -INFINITY;
    int s = 0;
    if (lane < deg) { s = srcs[r0 + lane]; e = leaky(as[s] + adn); }
    sr_sm[wv][lane] = s;
    float m = e;
    #pragma unroll
    for (int off = 32; off > 0; off >>= 1) m = fmaxf(m, __shfl_xor(m, off));
    float sc = (lane < deg) ? __expf(e - m) : 0.f;
    float ssum = sc;
    #pragma unroll
    for (int off = 32; off > 0; off >>= 1) ssum += __shfl_xor(ssum, off);
    al_sm[wv][lane] = sc / ssum;

    for (int base = 0; base < deg; base += 16) {
      #pragma unroll
      for (int u = 0; u < 4; ++u) {
        int idx = base + grp * 4 + u;
        bool vU = idx < deg;
        int jj = vU ? idx : 0;
        int   sU  = sr_sm[wv][jj];
        float alU = vU ? al_sm[wv][jj] : 0.f;
        uint2 hv = *(const uint2*)&Hm[(size_t)sU * 64 + cbase];
        float2 f0 = __half22float2(*(const __half2*)&hv.x);
        float2 f1 = __half22float2(*(const __half2*)&hv.y);
        a0 += f0.x * alU; a1 += f0.y * alU; a2 += f1.x * alU; a3 += f1.y * alU;
      }
    }
  } else {
    float mh = -INFINITY;
    for (int r = r0 + lane; r < r1; r += 64)
      mh = fmaxf(mh, leaky(as[srcs[r]] + adn));
    #pragma unroll
    for (int off = 32; off > 0; off >>= 1) mh = fmaxf(mh, __shfl_xor(mh, off));
    float ssum = 0.f;
    for (int r = r0 + lane; r < r1; r += 64)
      ssum += __expf(leaky(as[srcs[r]] + adn) - mh);
    #pragma unroll
    for (int off = 32; off > 0; off >>= 1) ssum += __shfl_xor(ssum, off);
    float inv = 1.f / ssum;
    for (int r = r0; r < r1; r += 8) {
      int rA = r + grp, rB = rA + 4;
      bool vA = rA < r1, vB = rB < r1;
      int sA = srcs[vA ? rA : r0];
      int sB = srcs[vB ? rB : r0];
      float alA = vA ? (__expf(leaky(as[sA] + adn) - mh) * inv) : 0.f;
      float alB = vB ? (__expf(leaky(as[sB] + adn) - mh) * inv) : 0.f;
      uint2 hvA = *(const uint2*)&Hm[(size_t)sA * 64 + cbase];
      uint2 hvB = *(const uint2*)&Hm[(size_t)sB * 64 + cbase];
      float2 fA0 = __half22float2(*(const __half2*)&hvA.x);
      float2 fA1 = __half22float2(*(const __half2*)&hvA.y);
      float2 fB0 = __half22float2(*(const __half2*)&hvB.x);
      float2 fB1 = __half22float2(*(const __half2*)&hvB.y);
      a0 += fA0.x * alA + fB0.x * alB; a1 += fA0.y * alA + fB0.y * alB;
      a2 += fA1.x * alA + fB1.x * alB; a3 += fA1.y * alA + fB1.y * alB;
    }
  }
  a0 += __shfl_xor(a0, 16); a0 += __shfl_xor(a0, 32);
  a1 += __shfl_xor(a1, 16); a1 += __shfl_xor(a1, 32);
  a2 += __shfl_xor(a2, 16); a2 += __shfl_xor(a2, 32);
  a3 += __shfl_xor(a3, 16); a3 += __shfl_xor(a3, 32);
  if (grp == 0) {
    float4 bv = *(const float4*)&bias[cbase];
    float4 o;
    o.x = a0 + bv.x; o.y = a1 + bv.y; o.z = a2 + bv.z; o.w = a3 + bv.w;
    *(float4*)&out[(size_t)n * 64 + cbase] = o;
  }
}

extern "C" void kernel_launch(void* const* d_in, const int* in_sizes, int n_in,
                              void* d_out, int out_size, void* d_ws, size_t ws_size,
                              hipStream_t stream) {
  const float* x   = (const float*)d_in[0];
  const int*   ei  = (const int*)d_in[1];
  // d_in[2] edge_weight: unused by GATConv (edge_dim unset)
  const float* W1  = (const float*)d_in[3];
  const float* aS1 = (const float*)d_in[4];
  const float* aD1 = (const float*)d_in[5];
  const float* b1  = (const float*)d_in[6];
  const float* W2  = (const float*)d_in[7];
  const float* aS2 = (const float*)d_in[8];
  const float* aD2 = (const float*)d_in[9];
  const float* b2  = (const float*)d_in[10];

  const int N  = in_sizes[0] / 128;
  const int E  = in_sizes[2];
  const int ET = E + N;
  const int NB = (N + 127) >> 7;              // 128-node buckets

  float* ws   = (float*)d_ws;
  __half* h1h = (__half*)ws;                  // N*128 halfs (= N*64 floats of space)
  float* out1 = ws + (size_t)N * 64;          // N*128 floats
  float* as1  = out1 + (size_t)N * 128;       // 4N
  float* ad1  = as1  + (size_t)4 * N;         // 4N
  float* as2  = ad1  + (size_t)4 * N;         // N
  float* ad2  = as2  + (size_t)N;             // N
  int*   lcnt    = (int*)(ad2 + (size_t)N);   // 32 (padded: [0]=small,[16]=big)
  int*   rowptr  = lcnt + 32;                 // N+1
  int*   bbase   = rowptr + N + 1;            // NB+1
  int*   blkpref = bbase + NB + 1;            // NB*NBLKA
  int*   small_list = blkpref + NB * NBLKA;   // N
  int*   big_list   = small_list + N;         // N
  int*   srcs   = big_list + N;               // ET
  int*   pairs  = (int*)ws;                   // ET ints, aliased onto h1h (dead before gemm1)
  __half* h2h  = h1h;                         // alias (h1h dead after agg1)
  float* out  = (float*)d_out;                // N*64

  const int gb  = (N + 63) / 64;              // gemm blocks
  const int sb  = (N + 15) / 16;              // small-agg blocks (worst case)
  const int bb  = (N + 3) / 4;                // big-agg blocks (worst case)

  // ---- CSR build: deterministic radix partition ----
  histc_k<<<NBLKA, 256, 0, stream>>>(ei, E, ET, blkpref, NB);
  scan_blk_k<<<NB, 256, 0, stream>>>(blkpref, bbase);
  scan_bkt_k<<<1, 512, 0, stream>>>(bbase, lcnt, rowptr, NB, N, ET);
  passA_k<<<NBLKA, 256, 0, stream>>>(ei, E, ET, bbase, blkpref, pairs, NB);
  passB_k<<<NB, 256, 0, stream>>>(pairs, bbase, rowptr, srcs,
                                  small_list, big_list, lcnt, N);

  // ---- layer 1 ----
  gemm1_k<<<gb, 256, 0, stream>>>(x, W1, aS1, aD1, h1h, as1, ad1, N);
  agg1_small_k<<<sb, 256, 0, stream>>>(rowptr, srcs, as1, ad1, h1h, b1, out1,
                                       small_list, lcnt);
  agg1_big_k<<<bb, 256, 0, stream>>>(rowptr, srcs, as1, ad1, h1h, b1, out1,
                                     big_list, lcnt);

  // ---- layer 2 ----
  gemm2_k<<<gb, 256, 0, stream>>>(out1, W2, aS2, aD2, h2h, as2, ad2, N);
  agg2_small_k<<<sb, 256, 0, stream>>>(rowptr, srcs, as2, ad2, h2h, b2, out,
                                       small_list, lcnt);
  agg2_big_k<<<bb, 256, 0, stream>>>(rowptr, srcs, as2, ad2, h2h, b2, out,
                                     big_list, lcnt);
}

// Round 11
// 234.997 us; speedup vs baseline: 3.1318x; 1.0380x over previous
//
#include <hip/hip_runtime.h>
#include <hip/hip_fp16.h>
#include <math.h>

// GAT (2 layers) on MI355X — radix CSR + merged degree-bucketed aggregation.
// h1/out1/h2 stored fp16 (gather + interlayer traffic halved); all softmax
// math and accumulation fp32. CSR: deterministic 2-pass radix partition by
// dst (no global atomics in edge passes). agg: one kernel per layer, block
// role split small(deg<=16: node per 16-lane group)/big(node per wave).

#define NEG_SLOPE 0.2f
#define NBLKA 256
#define MAXNB 512

__device__ __forceinline__ float leaky(float v) { return v > 0.f ? v : NEG_SLOPE * v; }

// ---------------- CSR build: radix partition by dst ----------------
__global__ __launch_bounds__(256) void histc_k(const int* __restrict__ ei, int E, int ET,
                                               int* __restrict__ blkpref, int NB) {
  __shared__ int lhist[MAXNB];
  int chunk = (ET + NBLKA - 1) / NBLKA;
  int e0 = blockIdx.x * chunk, e1 = min(ET, e0 + chunk);
  for (int b = threadIdx.x; b < NB; b += 256) lhist[b] = 0;
  __syncthreads();
  for (int e = e0 + threadIdx.x; e < e1; e += 256) {
    int d = (e < E) ? ei[E + e] : (e - E);
    atomicAdd(&lhist[d >> 7], 1);
  }
  __syncthreads();
  for (int b = threadIdx.x; b < NB; b += 256)
    blkpref[b * NBLKA + blockIdx.x] = lhist[b];
}

__global__ __launch_bounds__(256) void scan_blk_k(int* __restrict__ blkpref,
                                                  int* __restrict__ bbase) {
  __shared__ int sm[NBLKA];
  int b = blockIdx.x, t = threadIdx.x;
  int v = blkpref[b * NBLKA + t];
  sm[t] = v;
  __syncthreads();
  #pragma unroll
  for (int off = 1; off < NBLKA; off <<= 1) {
    int x = (t >= off) ? sm[t - off] : 0;
    __syncthreads();
    sm[t] += x;
    __syncthreads();
  }
  blkpref[b * NBLKA + t] = sm[t] - v;
  if (t == NBLKA - 1) bbase[b] = sm[t];
}

__global__ __launch_bounds__(512) void scan_bkt_k(int* __restrict__ bbase,
                                                  int* __restrict__ lcnt,
                                                  int* __restrict__ rowptr,
                                                  int NB, int N, int ET) {
  __shared__ int sm[512];
  int t = threadIdx.x;
  int v = (t < NB) ? bbase[t] : 0;
  sm[t] = v;
  __syncthreads();
  #pragma unroll
  for (int off = 1; off < 512; off <<= 1) {
    int x = (t >= off) ? sm[t - off] : 0;
    __syncthreads();
    sm[t] += x;
    __syncthreads();
  }
  int excl = sm[t] - v;
  if (t <= NB) bbase[t] = excl;
  if (t == 0) { lcnt[0] = 0; lcnt[16] = 0; rowptr[N] = ET; }
}

__global__ __launch_bounds__(256) void passA_k(const int* __restrict__ ei, int E, int ET,
                                               const int* __restrict__ bbase,
                                               const int* __restrict__ blkpref,
                                               int* __restrict__ pairs, int NB) {
  __shared__ int lcur[MAXNB];
  int chunk = (ET + NBLKA - 1) / NBLKA;
  int e0 = blockIdx.x * chunk, e1 = min(ET, e0 + chunk);
  for (int b = threadIdx.x; b < NB; b += 256)
    lcur[b] = bbase[b] + blkpref[b * NBLKA + blockIdx.x];
  __syncthreads();
  for (int e = e0 + threadIdx.x; e < e1; e += 256) {
    int s, d;
    if (e < E) { s = ei[e]; d = ei[E + e]; } else { s = d = e - E; }
    int b = d >> 7;
    int pos = atomicAdd(&lcur[b], 1);
    pairs[pos] = ((d & 127) << 17) | s;
  }
}

__global__ __launch_bounds__(256) void passB_k(const int* __restrict__ pairs,
                                               const int* __restrict__ bbase,
                                               int* __restrict__ rowptr,
                                               int* __restrict__ srcs,
                                               int* __restrict__ small_list,
                                               int* __restrict__ big_list,
                                               int* __restrict__ lcnt, int N) {
  __shared__ int ncnt[128], spre[128], lcur[128];
  __shared__ int wcS[2], wcB[2], bS, bB;
  int b = blockIdx.x, t = threadIdx.x;
  int nb0 = b << 7;
  int nn = min(128, N - nb0);
  int e0 = bbase[b], e1 = bbase[b + 1];
  if (t < 128) ncnt[t] = 0;
  __syncthreads();
  for (int r = e0 + t; r < e1; r += 256)
    atomicAdd(&ncnt[pairs[r] >> 17], 1);
  __syncthreads();
  if (t < 128) spre[t] = ncnt[t];
  __syncthreads();
  #pragma unroll
  for (int off = 1; off < 128; off <<= 1) {
    int x = (t < 128 && t >= off) ? spre[t - off] : 0;
    __syncthreads();
    if (t < 128) spre[t] += x;
    __syncthreads();
  }
  if (t < nn) {
    int base = e0 + spre[t] - ncnt[t];
    rowptr[nb0 + t] = base;
    lcur[t] = base;
  }
  __syncthreads();
  for (int r = e0 + t; r < e1; r += 256) {
    int p = pairs[r];
    int pos = atomicAdd(&lcur[p >> 17], 1);
    srcs[pos] = p & 0x1FFFF;
  }
  int lane = t & 63, wv = t >> 6;
  bool valid = (t < nn);
  int deg = valid ? ncnt[t] : 0;
  bool isS = valid && (deg <= 16);
  bool isB = valid && (deg > 16);
  unsigned long long ms = __ballot(isS);
  unsigned long long mb = __ballot(isB);
  if (lane == 0 && wv < 2) { wcS[wv] = __popcll(ms); wcB[wv] = __popcll(mb); }
  __syncthreads();
  if (t == 0) {
    bS = atomicAdd(&lcnt[0],  wcS[0] + wcS[1]);
    bB = atomicAdd(&lcnt[16], wcB[0] + wcB[1]);
  }
  __syncthreads();
  unsigned long long below = (lane == 0) ? 0ull : (~0ull >> (64 - lane));
  int offS = bS + ((wv == 1) ? wcS[0] : 0);
  int offB = bB + ((wv == 1) ? wcB[0] : 0);
  if (isS) small_list[offS + __popcll(ms & below)] = nb0 + t;
  if (isB) big_list[offB + __popcll(mb & below)]   = nb0 + t;
}

// ---------------- GEMM1 + alpha1: h1h (fp16) = X(fp32) @ W1 ----------------
__global__ __launch_bounds__(256) void gemm1_k(const float* __restrict__ X,
                                               const float* __restrict__ W,
                                               const float* __restrict__ aw_s,
                                               const float* __restrict__ aw_d,
                                               __half* __restrict__ Hh,
                                               float* __restrict__ as,
                                               float* __restrict__ ad, int N) {
  __shared__ float wl[32 * 128];
  __shared__ float xt[32][72];
  int cl = threadIdx.x & 31, rg = threadIdx.x >> 5;
  int c4 = cl * 4;
  int n0 = blockIdx.x * 64;
  float acc[8][4] = {};
  const float4* X4 = (const float4*)X;
  const float4* W4 = (const float4*)W;
  for (int k0 = 0; k0 < 128; k0 += 32) {
    __syncthreads();
    for (int i = threadIdx.x; i < 1024; i += 256)
      ((float4*)wl)[i] = W4[k0 * 32 + i];
    for (int i = threadIdx.x; i < 512; i += 256) {
      int r = i >> 3, kk4 = (i & 7) * 4;
      int n = n0 + r;
      float4 xv = (n < N) ? X4[(size_t)n * 32 + (k0 >> 2) + (i & 7)]
                          : make_float4(0.f, 0.f, 0.f, 0.f);
      xt[kk4 + 0][r] = xv.x; xt[kk4 + 1][r] = xv.y;
      xt[kk4 + 2][r] = xv.z; xt[kk4 + 3][r] = xv.w;
    }
    __syncthreads();
    #pragma unroll 8
    for (int kk = 0; kk < 32; ++kk) {
      float4 w4 = *(const float4*)&wl[kk * 128 + c4];
      float4 xa = *(const float4*)&xt[kk][rg * 8];
      float4 xb = *(const float4*)&xt[kk][rg * 8 + 4];
      float xr[8] = {xa.x, xa.y, xa.z, xa.w, xb.x, xb.y, xb.z, xb.w};
      #pragma unroll
      for (int j = 0; j < 8; ++j) {
        acc[j][0] += xr[j] * w4.x; acc[j][1] += xr[j] * w4.y;
        acc[j][2] += xr[j] * w4.z; acc[j][3] += xr[j] * w4.w;
      }
    }
  }
  float4 aws = *(const float4*)&aw_s[c4];
  float4 awd = *(const float4*)&aw_d[c4];
  #pragma unroll
  for (int j = 0; j < 8; ++j) {
    int n = n0 + rg * 8 + j;
    float ps = acc[j][0] * aws.x + acc[j][1] * aws.y + acc[j][2] * aws.z + acc[j][3] * aws.w;
    float pd = acc[j][0] * awd.x + acc[j][1] * awd.y + acc[j][2] * awd.z + acc[j][3] * awd.w;
    ps += __shfl_xor(ps, 1); ps += __shfl_xor(ps, 2); ps += __shfl_xor(ps, 4);
    pd += __shfl_xor(pd, 1); pd += __shfl_xor(pd, 2); pd += __shfl_xor(pd, 4);
    if (n < N) {
      __half2* dst = (__half2*)&Hh[(size_t)n * 128 + c4];
      dst[0] = __floats2half2_rn(acc[j][0], acc[j][1]);
      dst[1] = __floats2half2_rn(acc[j][2], acc[j][3]);
      if ((cl & 7) == 0) {
        as[n * 4 + (cl >> 3)] = ps;
        ad[n * 4 + (cl >> 3)] = pd;
      }
    }
  }
}

// ---------------- GEMM2 + alpha2: h2h (fp16) = X(fp16) @ W2 ----------------
__global__ __launch_bounds__(256) void gemm2_k(const __half* __restrict__ X,
                                               const float* __restrict__ W,
                                               const float* __restrict__ aw_s,
                                               const float* __restrict__ aw_d,
                                               __half* __restrict__ Hh,
                                               float* __restrict__ as,
                                               float* __restrict__ ad, int N) {
  __shared__ float wl[32 * 64];
  __shared__ float xt[32][72];
  int cl = threadIdx.x & 15, rg = threadIdx.x >> 4;
  int c4 = cl * 4;
  int n0 = blockIdx.x * 64;
  float acc[4][4] = {};
  const uint4* X8 = (const uint4*)X;    // 8 halfs per load; row = 16 uint4
  const float4* W4 = (const float4*)W;
  for (int k0 = 0; k0 < 128; k0 += 32) {
    __syncthreads();
    for (int i = threadIdx.x; i < 512; i += 256)
      ((float4*)wl)[i] = W4[k0 * 16 + i];
    for (int i = threadIdx.x; i < 256; i += 256) {
      int r = i >> 2, kk8 = (i & 3) * 8;
      int n = n0 + r;
      uint4 hv = (n < N) ? X8[(size_t)n * 16 + (k0 >> 3) + (i & 3)]
                         : make_uint4(0, 0, 0, 0);
      float2 f0 = __half22float2(*(const __half2*)&hv.x);
      float2 f1 = __half22float2(*(const __half2*)&hv.y);
      float2 f2 = __half22float2(*(const __half2*)&hv.z);
      float2 f3 = __half22float2(*(const __half2*)&hv.w);
      xt[kk8 + 0][r] = f0.x; xt[kk8 + 1][r] = f0.y;
      xt[kk8 + 2][r] = f1.x; xt[kk8 + 3][r] = f1.y;
      xt[kk8 + 4][r] = f2.x; xt[kk8 + 5][r] = f2.y;
      xt[kk8 + 6][r] = f3.x; xt[kk8 + 7][r] = f3.y;
    }
    __syncthreads();
    #pragma unroll 8
    for (int kk = 0; kk < 32; ++kk) {
      float4 w4 = *(const float4*)&wl[kk * 64 + c4];
      float4 xa = *(const float4*)&xt[kk][rg * 4];
      float xr[4] = {xa.x, xa.y, xa.z, xa.w};
      #pragma unroll
      for (int j = 0; j < 4; ++j) {
        acc[j][0] += xr[j] * w4.x; acc[j][1] += xr[j] * w4.y;
        acc[j][2] += xr[j] * w4.z; acc[j][3] += xr[j] * w4.w;
      }
    }
  }
  float4 aws = *(const float4*)&aw_s[c4];
  float4 awd = *(const float4*)&aw_d[c4];
  #pragma unroll
  for (int j = 0; j < 4; ++j) {
    int n = n0 + rg * 4 + j;
    float ps = acc[j][0] * aws.x + acc[j][1] * aws.y + acc[j][2] * aws.z + acc[j][3] * aws.w;
    float pd = acc[j][0] * awd.x + acc[j][1] * awd.y + acc[j][2] * awd.z + acc[j][3] * awd.w;
    ps += __shfl_xor(ps, 1); ps += __shfl_xor(ps, 2);
    ps += __shfl_xor(ps, 4); ps += __shfl_xor(ps, 8);
    pd += __shfl_xor(pd, 1); pd += __shfl_xor(pd, 2);
    pd += __shfl_xor(pd, 4); pd += __shfl_xor(pd, 8);
    if (n < N) {
      __half2* dst = (__half2*)&Hh[(size_t)n * 64 + c4];
      dst[0] = __floats2half2_rn(acc[j][0], acc[j][1]);
      dst[1] = __floats2half2_rn(acc[j][2], acc[j][3]);
      if (cl == 0) { as[n] = ps; ad[n] = pd; }
    }
  }
}

__device__ __forceinline__ void load8h(const __half* p, float* f) {
  uint4 hv = *(const uint4*)p;
  float2 f0 = __half22float2(*(const __half2*)&hv.x);
  float2 f1 = __half22float2(*(const __half2*)&hv.y);
  float2 f2 = __half22float2(*(const __half2*)&hv.z);
  float2 f3 = __half22float2(*(const __half2*)&hv.w);
  f[0] = f0.x; f[1] = f0.y; f[2] = f1.x; f[3] = f1.y;
  f[4] = f2.x; f[5] = f2.y; f[6] = f3.x; f[7] = f3.y;
}

// ---------------- layer-1 merged aggregation (out fp16) ----------------
__global__ __launch_bounds__(256) void agg1_k(const int* __restrict__ rowptr,
                                              const int* __restrict__ srcs,
                                              const float* __restrict__ as,
                                              const float* __restrict__ ad,
                                              const __half* __restrict__ Hm,
                                              const float* __restrict__ bias,
                                              __half* __restrict__ out,
                                              const int* __restrict__ small_list,
                                              const int* __restrict__ big_list,
                                              const int* __restrict__ lcnt, int SB) {
  if (blockIdx.x < (unsigned)SB) {
    // ---- small role: node per 16-lane group ----
    __shared__ float al_sm[16][17][4];
    __shared__ int   sr_sm[16][16];
    int g  = threadIdx.x >> 4;
    int gl = threadIdx.x & 15;
    int gidx = blockIdx.x * 16 + g;
    if (gidx >= lcnt[0]) return;
    int n = small_list[gidx];
    int r0 = rowptr[n];
    int deg = rowptr[n + 1] - r0;
    float4 adn = *(const float4*)&ad[n * 4];

    float e0 = -INFINITY, e1 = -INFINITY, e2 = -INFINITY, e3 = -INFINITY;
    int s = 0;
    if (gl < deg) {
      s = srcs[r0 + gl];
      float4 av = *(const float4*)&as[s * 4];
      e0 = leaky(av.x + adn.x); e1 = leaky(av.y + adn.y);
      e2 = leaky(av.z + adn.z); e3 = leaky(av.w + adn.w);
    }
    sr_sm[g][gl] = s;
    float m0 = e0, m1 = e1, m2 = e2, m3 = e3;
    #pragma unroll
    for (int off = 8; off > 0; off >>= 1) {
      m0 = fmaxf(m0, __shfl_xor(m0, off, 16)); m1 = fmaxf(m1, __shfl_xor(m1, off, 16));
      m2 = fmaxf(m2, __shfl_xor(m2, off, 16)); m3 = fmaxf(m3, __shfl_xor(m3, off, 16));
    }
    float sc0 = (gl < deg) ? __expf(e0 - m0) : 0.f;
    float sc1 = (gl < deg) ? __expf(e1 - m1) : 0.f;
    float sc2 = (gl < deg) ? __expf(e2 - m2) : 0.f;
    float sc3 = (gl < deg) ? __expf(e3 - m3) : 0.f;
    float s0 = sc0, s1 = sc1, s2 = sc2, s3 = sc3;
    #pragma unroll
    for (int off = 8; off > 0; off >>= 1) {
      s0 += __shfl_xor(s0, off, 16); s1 += __shfl_xor(s1, off, 16);
      s2 += __shfl_xor(s2, off, 16); s3 += __shfl_xor(s3, off, 16);
    }
    *(float4*)&al_sm[g][gl][0] =
        make_float4(sc0 / s0, sc1 / s1, sc2 / s2, sc3 / s3);

    int h = gl >> 2;
    int cbase = gl * 8;
    float a0 = 0.f, a1 = 0.f, a2 = 0.f, a3 = 0.f,
          a4 = 0.f, a5 = 0.f, a6 = 0.f, a7 = 0.f;
    for (int j = 0; j < deg; j += 4) {
      #pragma unroll
      for (int u = 0; u < 4; ++u) {
        int idx = j + u;
        bool vU = idx < deg;
        int jj = vU ? idx : 0;
        int   sU  = sr_sm[g][jj];
        float alU = vU ? al_sm[g][jj][h] : 0.f;
        float f[8];
        load8h(&Hm[(size_t)sU * 128 + cbase], f);
        a0 += f[0] * alU; a1 += f[1] * alU; a2 += f[2] * alU; a3 += f[3] * alU;
        a4 += f[4] * alU; a5 += f[5] * alU; a6 += f[6] * alU; a7 += f[7] * alU;
      }
    }
    float4 b0 = *(const float4*)&bias[cbase];
    float4 b1 = *(const float4*)&bias[cbase + 4];
    __half2* dst = (__half2*)&out[(size_t)n * 128 + cbase];
    dst[0] = __floats2half2_rn(fmaxf(a0 + b0.x, 0.f), fmaxf(a1 + b0.y, 0.f));
    dst[1] = __floats2half2_rn(fmaxf(a2 + b0.z, 0.f), fmaxf(a3 + b0.w, 0.f));
    dst[2] = __floats2half2_rn(fmaxf(a4 + b1.x, 0.f), fmaxf(a5 + b1.y, 0.f));
    dst[3] = __floats2half2_rn(fmaxf(a6 + b1.z, 0.f), fmaxf(a7 + b1.w, 0.f));
    return;
  }
  // ---- big role: node per wave ----
  __shared__ float al_sm[4][64][4];
  __shared__ int   sr_sm[4][64];
  int wv = threadIdx.x >> 6, lane = threadIdx.x & 63;
  int widx = (blockIdx.x - SB) * 4 + wv;
  if (widx >= lcnt[16]) return;
  int n = big_list[widx];
  int r0 = rowptr[n], r1 = rowptr[n + 1];
  int deg = r1 - r0;
  int grp = lane >> 4, gl = lane & 15, h = gl >> 2;
  int cbase = gl * 8;
  float4 adn = *(const float4*)&ad[n * 4];

  float a0 = 0.f, a1 = 0.f, a2 = 0.f, a3 = 0.f,
        a4 = 0.f, a5 = 0.f, a6 = 0.f, a7 = 0.f;

  if (deg <= 64) {
    float e0 = -INFINITY, e1 = -INFINITY, e2 = -INFINITY, e3 = -INFINITY;
    int s = 0;
    if (lane < deg) {
      s = srcs[r0 + lane];
      float4 av = *(const float4*)&as[s * 4];
      e0 = leaky(av.x + adn.x); e1 = leaky(av.y + adn.y);
      e2 = leaky(av.z + adn.z); e3 = leaky(av.w + adn.w);
    }
    sr_sm[wv][lane] = s;
    float m0 = e0, m1 = e1, m2 = e2, m3 = e3;
    #pragma unroll
    for (int off = 32; off > 0; off >>= 1) {
      m0 = fmaxf(m0, __shfl_xor(m0, off)); m1 = fmaxf(m1, __shfl_xor(m1, off));
      m2 = fmaxf(m2, __shfl_xor(m2, off)); m3 = fmaxf(m3, __shfl_xor(m3, off));
    }
    float sc0 = (lane < deg) ? __expf(e0 - m0) : 0.f;
    float sc1 = (lane < deg) ? __expf(e1 - m1) : 0.f;
    float sc2 = (lane < deg) ? __expf(e2 - m2) : 0.f;
    float sc3 = (lane < deg) ? __expf(e3 - m3) : 0.f;
    float s0 = sc0, s1 = sc1, s2 = sc2, s3 = sc3;
    #pragma unroll
    for (int off = 32; off > 0; off >>= 1) {
      s0 += __shfl_xor(s0, off); s1 += __shfl_xor(s1, off);
      s2 += __shfl_xor(s2, off); s3 += __shfl_xor(s3, off);
    }
    *(float4*)&al_sm[wv][lane][0] =
        make_float4(sc0 / s0, sc1 / s1, sc2 / s2, sc3 / s3);

    for (int base = 0; base < deg; base += 16) {
      #pragma unroll
      for (int u = 0; u < 4; ++u) {
        int idx = base + grp * 4 + u;
        bool vU = idx < deg;
        int jj = vU ? idx : 0;
        int   sU  = sr_sm[wv][jj];
        float alU = vU ? al_sm[wv][jj][h] : 0.f;
        float f[8];
        load8h(&Hm[(size_t)sU * 128 + cbase], f);
        a0 += f[0] * alU; a1 += f[1] * alU; a2 += f[2] * alU; a3 += f[3] * alU;
        a4 += f[4] * alU; a5 += f[5] * alU; a6 += f[6] * alU; a7 += f[7] * alU;
      }
    }
  } else {
    float m0 = -INFINITY, m1 = -INFINITY, m2 = -INFINITY, m3 = -INFINITY;
    for (int r = r0 + lane; r < r1; r += 64) {
      int s = srcs[r];
      float4 av = *(const float4*)&as[s * 4];
      m0 = fmaxf(m0, leaky(av.x + adn.x)); m1 = fmaxf(m1, leaky(av.y + adn.y));
      m2 = fmaxf(m2, leaky(av.z + adn.z)); m3 = fmaxf(m3, leaky(av.w + adn.w));
    }
    #pragma unroll
    for (int off = 32; off > 0; off >>= 1) {
      m0 = fmaxf(m0, __shfl_xor(m0, off)); m1 = fmaxf(m1, __shfl_xor(m1, off));
      m2 = fmaxf(m2, __shfl_xor(m2, off)); m3 = fmaxf(m3, __shfl_xor(m3, off));
    }
    float s0 = 0.f, s1 = 0.f, s2 = 0.f, s3 = 0.f;
    for (int r = r0 + lane; r < r1; r += 64) {
      int s = srcs[r];
      float4 av = *(const float4*)&as[s * 4];
      s0 += __expf(leaky(av.x + adn.x) - m0); s1 += __expf(leaky(av.y + adn.y) - m1);
      s2 += __expf(leaky(av.z + adn.z) - m2); s3 += __expf(leaky(av.w + adn.w) - m3);
    }
    #pragma unroll
    for (int off = 32; off > 0; off >>= 1) {
      s0 += __shfl_xor(s0, off); s1 += __shfl_xor(s1, off);
      s2 += __shfl_xor(s2, off); s3 += __shfl_xor(s3, off);
    }
    float mhh = (h == 0) ? m0 : (h == 1) ? m1 : (h == 2) ? m2 : m3;
    float inv = 1.f / ((h == 0) ? s0 : (h == 1) ? s1 : (h == 2) ? s2 : s3);
    float adh = (h == 0) ? adn.x : (h == 1) ? adn.y : (h == 2) ? adn.z : adn.w;
    for (int r = r0; r < r1; r += 8) {
      int rA = r + grp, rB = rA + 4;
      bool vA = rA < r1, vB = rB < r1;
      int sA = srcs[vA ? rA : r0];
      int sB = srcs[vB ? rB : r0];
      float avA = as[sA * 4 + h], avB = as[sB * 4 + h];
      float alA = vA ? (__expf(leaky(avA + adh) - mhh) * inv) : 0.f;
      float alB = vB ? (__expf(leaky(avB + adh) - mhh) * inv) : 0.f;
      float fA[8], fB[8];
      load8h(&Hm[(size_t)sA * 128 + cbase], fA);
      load8h(&Hm[(size_t)sB * 128 + cbase], fB);
      a0 += fA[0] * alA + fB[0] * alB; a1 += fA[1] * alA + fB[1] * alB;
      a2 += fA[2] * alA + fB[2] * alB; a3 += fA[3] * alA + fB[3] * alB;
      a4 += fA[4] * alA + fB[4] * alB; a5 += fA[5] * alA + fB[5] * alB;
      a6 += fA[6] * alA + fB[6] * alB; a7 += fA[7] * alA + fB[7] * alB;
    }
  }
  a0 += __shfl_xor(a0, 16); a0 += __shfl_xor(a0, 32);
  a1 += __shfl_xor(a1, 16); a1 += __shfl_xor(a1, 32);
  a2 += __shfl_xor(a2, 16); a2 += __shfl_xor(a2, 32);
  a3 += __shfl_xor(a3, 16); a3 += __shfl_xor(a3, 32);
  a4 += __shfl_xor(a4, 16); a4 += __shfl_xor(a4, 32);
  a5 += __shfl_xor(a5, 16); a5 += __shfl_xor(a5, 32);
  a6 += __shfl_xor(a6, 16); a6 += __shfl_xor(a6, 32);
  a7 += __shfl_xor(a7, 16); a7 += __shfl_xor(a7, 32);
  if (grp == 0) {
    float4 b0 = *(const float4*)&bias[cbase];
    float4 b1 = *(const float4*)&bias[cbase + 4];
    __half2* dst = (__half2*)&out[(size_t)n * 128 + cbase];
    dst[0] = __floats2half2_rn(fmaxf(a0 + b0.x, 0.f), fmaxf(a1 + b0.y, 0.f));
    dst[1] = __floats2half2_rn(fmaxf(a2 + b0.z, 0.f), fmaxf(a3 + b0.w, 0.f));
    dst[2] = __floats2half2_rn(fmaxf(a4 + b1.x, 0.f), fmaxf(a5 + b1.y, 0.f));
    dst[3] = __floats2half2_rn(fmaxf(a6 + b1.z, 0.f), fmaxf(a7 + b1.w, 0.f));
  }
}

// ---------------- layer-2 merged aggregation (out fp32 = d_out) ----------------
__global__ __launch_bounds__(256) void agg2_k(const int* __restrict__ rowptr,
                                              const int* __restrict__ srcs,
                                              const float* __restrict__ as,
                                              const float* __restrict__ ad,
                                              const __half* __restrict__ Hm,
                                              const float* __restrict__ bias,
                                              float* __restrict__ out,
                                              const int* __restrict__ small_list,
                                              const int* __restrict__ big_list,
                                              const int* __restrict__ lcnt, int SB) {
  if (blockIdx.x < (unsigned)SB) {
    __shared__ float al_sm[16][17];
    __shared__ int   sr_sm[16][16];
    int g  = threadIdx.x >> 4;
    int gl = threadIdx.x & 15;
    int gidx = blockIdx.x * 16 + g;
    if (gidx >= lcnt[0]) return;
    int n = small_list[gidx];
    int r0 = rowptr[n];
    int deg = rowptr[n + 1] - r0;
    float adn = ad[n];

    float e = -INFINITY;
    int s = 0;
    if (gl < deg) { s = srcs[r0 + gl]; e = leaky(as[s] + adn); }
    sr_sm[g][gl] = s;
    float m = e;
    #pragma unroll
    for (int off = 8; off > 0; off >>= 1) m = fmaxf(m, __shfl_xor(m, off, 16));
    float sc = (gl < deg) ? __expf(e - m) : 0.f;
    float ssum = sc;
    #pragma unroll
    for (int off = 8; off > 0; off >>= 1) ssum += __shfl_xor(ssum, off, 16);
    al_sm[g][gl] = sc / ssum;

    int cbase = gl * 4;
    float a0 = 0.f, a1 = 0.f, a2 = 0.f, a3 = 0.f;
    for (int j = 0; j < deg; j += 4) {
      #pragma unroll
      for (int u = 0; u < 4; ++u) {
        int idx = j + u;
        bool vU = idx < deg;
        int jj = vU ? idx : 0;
        int   sU  = sr_sm[g][jj];
        float alU = vU ? al_sm[g][jj] : 0.f;
        uint2 hv = *(const uint2*)&Hm[(size_t)sU * 64 + cbase];
        float2 f0 = __half22float2(*(const __half2*)&hv.x);
        float2 f1 = __half22float2(*(const __half2*)&hv.y);
        a0 += f0.x * alU; a1 += f0.y * alU; a2 += f1.x * alU; a3 += f1.y * alU;
      }
    }
    float4 bv = *(const float4*)&bias[cbase];
    float4 o;
    o.x = a0 + bv.x; o.y = a1 + bv.y; o.z = a2 + bv.z; o.w = a3 + bv.w;
    *(float4*)&out[(size_t)n * 64 + cbase] = o;
    return;
  }
  __shared__ float al_sm[4][64];
  __shared__ int   sr_sm[4][64];
  int wv = threadIdx.x >> 6, lane = threadIdx.x & 63;
  int widx = (blockIdx.x - SB) * 4 + wv;
  if (widx >= lcnt[16]) return;
  int n = big_list[widx];
  int r0 = rowptr[n], r1 = rowptr[n + 1];
  int deg = r1 - r0;
  int grp = lane >> 4, gl = lane & 15;
  int cbase = gl * 4;
  float adn = ad[n];

  float a0 = 0.f, a1 = 0.f, a2 = 0.f, a3 = 0.f;

  if (deg <= 64) {
    float e = -INFINITY;
    int s = 0;
    if (lane < deg) { s = srcs[r0 + lane]; e = leaky(as[s] + adn); }
    sr_sm[wv][lane] = s;
    float m = e;
    #pragma unroll
    for (int off = 32; off > 0; off >>= 1) m = fmaxf(m, __shfl_xor(m, off));
    float sc = (lane < deg) ? __expf(e - m) : 0.f;
    float ssum = sc;
    #pragma unroll
    for (int off = 32; off > 0; off >>= 1) ssum += __shfl_xor(ssum, off);
    al_sm[wv][lane] = sc / ssum;

    for (int base = 0; base < deg; base += 16) {
      #pragma unroll
      for (int u = 0; u < 4; ++u) {
        int idx = base + grp * 4 + u;
        bool vU = idx < deg;
        int jj = vU ? idx : 0;
        int   sU  = sr_sm[wv][jj];
        float alU = vU ? al_sm[wv][jj] : 0.f;
        uint2 hv = *(const uint2*)&Hm[(size_t)sU * 64 + cbase];
        float2 f0 = __half22float2(*(const __half2*)&hv.x);
        float2 f1 = __half22float2(*(const __half2*)&hv.y);
        a0 += f0.x * alU; a1 += f0.y * alU; a2 += f1.x * alU; a3 += f1.y * alU;
      }
    }
  } else {
    float mh = -INFINITY;
    for (int r = r0 + lane; r < r1; r += 64)
      mh = fmaxf(mh, leaky(as[srcs[r]] + adn));
    #pragma unroll
    for (int off = 32; off > 0; off >>= 1) mh = fmaxf(mh, __shfl_xor(mh, off));
    float ssum = 0.f;
    for (int r = r0 + lane; r < r1; r += 64)
      ssum += __expf(leaky(as[srcs[r]] + adn) - mh);
    #pragma unroll
    for (int off = 32; off > 0; off >>= 1) ssum += __shfl_xor(ssum, off);
    float inv = 1.f / ssum;
    for (int r = r0; r < r1; r += 8) {
      int rA = r + grp, rB = rA + 4;
      bool vA = rA < r1, vB = rB < r1;
      int sA = srcs[vA ? rA : r0];
      int sB = srcs[vB ? rB : r0];
      float alA = vA ? (__expf(leaky(as[sA] + adn) - mh) * inv) : 0.f;
      float alB = vB ? (__expf(leaky(as[sB] + adn) - mh) * inv) : 0.f;
      uint2 hvA = *(const uint2*)&Hm[(size_t)sA * 64 + cbase];
      uint2 hvB = *(const uint2*)&Hm[(size_t)sB * 64 + cbase];
      float2 fA0 = __half22float2(*(const __half2*)&hvA.x);
      float2 fA1 = __half22float2(*(const __half2*)&hvA.y);
      float2 fB0 = __half22float2(*(const __half2*)&hvB.x);
      float2 fB1 = __half22float2(*(const __half2*)&hvB.y);
      a0 += fA0.x * alA + fB0.x * alB; a1 += fA0.y * alA + fB0.y * alB;
      a2 += fA1.x * alA + fB1.x * alB; a3 += fA1.y * alA + fB1.y * alB;
    }
  }
  a0 += __shfl_xor(a0, 16); a0 += __shfl_xor(a0, 32);
  a1 += __shfl_xor(a1, 16); a1 += __shfl_xor(a1, 32);
  a2 += __shfl_xor(a2, 16); a2 += __shfl_xor(a2, 32);
  a3 += __shfl_xor(a3, 16); a3 += __shfl_xor(a3, 32);
  if (grp == 0) {
    float4 bv = *(const float4*)&bias[cbase];
    float4 o;
    o.x = a0 + bv.x; o.y = a1 + bv.y; o.z = a2 + bv.z; o.w = a3 + bv.w;
    *(float4*)&out[(size_t)n * 64 + cbase] = o;
  }
}

extern "C" void kernel_launch(void* const* d_in, const int* in_sizes, int n_in,
                              void* d_out, int out_size, void* d_ws, size_t ws_size,
                              hipStream_t stream) {
  const float* x   = (const float*)d_in[0];
  const int*   ei  = (const int*)d_in[1];
  // d_in[2] edge_weight: unused by GATConv (edge_dim unset)
  const float* W1  = (const float*)d_in[3];
  const float* aS1 = (const float*)d_in[4];
  const float* aD1 = (const float*)d_in[5];
  const float* b1  = (const float*)d_in[6];
  const float* W2  = (const float*)d_in[7];
  const float* aS2 = (const float*)d_in[8];
  const float* aD2 = (const float*)d_in[9];
  const float* b2  = (const float*)d_in[10];

  const int N  = in_sizes[0] / 128;
  const int E  = in_sizes[2];
  const int ET = E + N;
  const int NB = (N + 127) >> 7;

  float* ws    = (float*)d_ws;
  __half* h1h  = (__half*)ws;                  // N*128 halfs
  __half* o1h  = (__half*)(ws + (size_t)N * 64);  // N*128 halfs (out1, fp16)
  float* as1   = ws + (size_t)N * 128;         // 4N  (after h1h+o1h = N*128 floats)
  float* ad1   = as1  + (size_t)4 * N;         // 4N
  float* as2   = ad1  + (size_t)4 * N;         // N
  float* ad2   = as2  + (size_t)N;             // N
  int*   lcnt    = (int*)(ad2 + (size_t)N);    // 32
  int*   rowptr  = lcnt + 32;                  // N+1
  int*   bbase   = rowptr + N + 1;             // NB+1
  int*   blkpref = bbase + NB + 1;             // NB*NBLKA
  int*   small_list = blkpref + NB * NBLKA;    // N
  int*   big_list   = small_list + N;          // N
  int*   srcs   = big_list + N;                // ET
  int*   pairs  = (int*)ws;                    // ET ints, aliased onto h1h
  __half* h2h  = h1h;                          // alias (h1h dead after agg1)
  float* out  = (float*)d_out;                 // N*64

  const int gb = (N + 63) / 64;
  const int sb = (N + 15) / 16;
  const int bb = (N + 3) / 4;

  // ---- CSR build ----
  histc_k<<<NBLKA, 256, 0, stream>>>(ei, E, ET, blkpref, NB);
  scan_blk_k<<<NB, 256, 0, stream>>>(blkpref, bbase);
  scan_bkt_k<<<1, 512, 0, stream>>>(bbase, lcnt, rowptr, NB, N, ET);
  passA_k<<<NBLKA, 256, 0, stream>>>(ei, E, ET, bbase, blkpref, pairs, NB);
  passB_k<<<NB, 256, 0, stream>>>(pairs, bbase, rowptr, srcs,
                                  small_list, big_list, lcnt, N);

  // ---- layer 1 ----
  gemm1_k<<<gb, 256, 0, stream>>>(x, W1, aS1, aD1, h1h, as1, ad1, N);
  agg1_k<<<sb + bb, 256, 0, stream>>>(rowptr, srcs, as1, ad1, h1h, b1, o1h,
                                      small_list, big_list, lcnt, sb);

  // ---- layer 2 ----
  gemm2_k<<<gb, 256, 0, stream>>>(o1h, W2, aS2, aD2, h2h, as2, ad2, N);
  agg2_k<<<sb + bb, 256, 0, stream>>>(rowptr, srcs, as2, ad2, h2h, b2, out,
                                      small_list, big_list, lcnt, sb);
}